// Round 1
// baseline (1222.089 us; speedup 1.0000x reference)
//
#include <hip/hip_runtime.h>
#include <hip/hip_bf16.h>
#include <math.h>

#define B_ 2
#define T_ 1024
#define D_ 256
#define N_ 1024
#define H_ 8
#define HD_ 128
#define K_ 32
#define VOCAB_ 32000
#define TC_ 16

static __device__ __forceinline__ float geluf(float x) {
    return 0.5f * x * (1.0f + erff(x * 0.70710678118654752f));
}

// ---------------- embed + quantized RoPE ----------------
__global__ void embed_rope_kernel(const int* __restrict__ tokens,
                                  const float* __restrict__ emb,
                                  const float* __restrict__ field_init,
                                  float* __restrict__ x) {
    int bt = blockIdx.x;          // b*T + t
    int d = threadIdx.x;          // 0..255
    int t = bt & (T_ - 1);
    int tok = tokens[bt];
    float v = emb[(long)tok * D_ + d] + field_init[d];
    float partner = __shfl_xor(v, 1);
    float rot = (d & 1) ? partner : -partner;   // x_rot[2i]=-x[2i+1], x_rot[2i+1]=x[2i]
    // freq = (2^16)^(-(d&~1)/256) / (2*pi)
    float freq = exp2f(-0.0625f * (float)(d & ~1)) * (1.0f / 6.283185307179586f);
    float ph = fmodf((float)t * freq, 1.0f) * 6.283185307179586f;
    x[(long)bt * D_ + d] = v * cosf(ph) + rot * sinf(ph);
}

// ---------------- dual LayerNorm (shared mean/var) ----------------
__global__ void ln_dual_kernel(const float* __restrict__ x,
                               const float* __restrict__ g1, const float* __restrict__ b1,
                               const float* __restrict__ g2, const float* __restrict__ b2,
                               float* __restrict__ y1, float* __restrict__ y2) {
    int row = blockIdx.x;
    int d = threadIdx.x;
    float v = x[(long)row * D_ + d];
    __shared__ float red[4];
    int lane = d & 63, wid = d >> 6;
    float s = v;
    #pragma unroll
    for (int off = 32; off; off >>= 1) s += __shfl_xor(s, off);
    if (lane == 0) red[wid] = s;
    __syncthreads();
    float mu = (red[0] + red[1] + red[2] + red[3]) * (1.0f / D_);
    float dv = v - mu;
    float s2 = dv * dv;
    #pragma unroll
    for (int off = 32; off; off >>= 1) s2 += __shfl_xor(s2, off);
    __syncthreads();
    if (lane == 0) red[wid] = s2;
    __syncthreads();
    float var = (red[0] + red[1] + red[2] + red[3]) * (1.0f / D_);
    float rstd = rsqrtf(var + 1e-5f);
    float nv = dv * rstd;
    y1[(long)row * D_ + d] = nv * g1[d] + b1[d];
    if (y2) y2[(long)row * D_ + d] = nv * g2[d] + b2[d];
}

// ---------------- generic tiled f32 GEMM: C = act(A@B + bias) ----------------
#define BM 64
#define BN 64
#define BK 16

template<int ACT>  // 0 none, 1 relu, 2 gelu
__global__ __launch_bounds__(256) void gemm_kernel(
    const float* __restrict__ A, int lda, long bsA,
    const float* __restrict__ Bm, int ldb, long bsB,
    const float* __restrict__ bias,
    float* __restrict__ C, int ldc, long bsC,
    int M, int N, int Kd) {
    int z = blockIdx.z;
    A += (long)z * bsA; Bm += (long)z * bsB; C += (long)z * bsC;
    __shared__ float As[BK][BM];
    __shared__ float Bs[BK][BN];
    int tid = threadIdx.x;
    int row0 = blockIdx.y * BM, col0 = blockIdx.x * BN;
    int am = tid >> 2, ak = (tid & 3) << 2;
    int bk = tid >> 4, bn = (tid & 15) << 2;
    int ty = tid >> 4, tx = tid & 15;
    float acc[4][4] = {};
    for (int k0 = 0; k0 < Kd; k0 += BK) {
        float4 av = make_float4(0.f, 0.f, 0.f, 0.f);
        if (row0 + am < M)
            av = *(const float4*)(A + (long)(row0 + am) * lda + k0 + ak);
        float4 bv = *(const float4*)(Bm + (long)(k0 + bk) * ldb + col0 + bn);
        __syncthreads();
        As[ak + 0][am] = av.x; As[ak + 1][am] = av.y;
        As[ak + 2][am] = av.z; As[ak + 3][am] = av.w;
        *(float4*)&Bs[bk][bn] = bv;
        __syncthreads();
        #pragma unroll
        for (int kk = 0; kk < BK; ++kk) {
            float4 a4 = *(const float4*)&As[kk][ty << 2];
            float4 b4 = *(const float4*)&Bs[kk][tx << 2];
            float a[4] = {a4.x, a4.y, a4.z, a4.w};
            float b[4] = {b4.x, b4.y, b4.z, b4.w};
            #pragma unroll
            for (int i = 0; i < 4; ++i)
                #pragma unroll
                for (int j = 0; j < 4; ++j)
                    acc[i][j] = fmaf(a[i], b[j], acc[i][j]);
        }
    }
    #pragma unroll
    for (int i = 0; i < 4; ++i) {
        int row = row0 + (ty << 2) + i;
        if (row >= M) break;
        #pragma unroll
        for (int j = 0; j < 4; ++j) {
            int col = col0 + (tx << 2) + j;
            float v = acc[i][j] + (bias ? bias[col] : 0.0f);
            if (ACT == 1) v = fmaxf(v, 0.0f);
            if (ACT == 2) v = geluf(v);
            C[(long)row * ldc + col] = v;
        }
    }
}

// ---------------- sig reduction (two stage) ----------------
__global__ void sig_stage1(const float* __restrict__ qs,
                           float* __restrict__ ps, float* __restrict__ ps8) {
    int bn = blockIdx.x * 256 + threadIdx.x;  // 0..2047  (b*1024+n)
    int tc = blockIdx.y;
    int b = bn >> 10, n = bn & 1023;
    float s = 0.f, s8 = 0.f;
    int t0 = tc * (T_ / TC_);
    for (int t = t0; t < t0 + T_ / TC_; ++t) {
        float v = qs[((long)(b * T_ + t) << 10) + n];
        s += v;
        if ((t & 7) == 0) s8 += v;
    }
    ps[tc * 2048 + bn] = s;
    ps8[tc * 2048 + bn] = s8;
}

__global__ void sig_stage2(const float* __restrict__ ps, const float* __restrict__ ps8,
                           float* __restrict__ sig) {
    int bn = blockIdx.x * 256 + threadIdx.x;
    float s = 0.f, s8 = 0.f;
    for (int tc = 0; tc < TC_; ++tc) { s += ps[tc * 2048 + bn]; s8 += ps8[tc * 2048 + bn]; }
    sig[bn] = s * (1.0f / T_) + 0.5f * s8 * (1.0f / (T_ / 8));
}

// ---------------- metric = softplus(base + 0.1*mod) + 1e-6 ----------------
__global__ void metric_kernel(const float* __restrict__ base_metric,
                              const float* __restrict__ mod, float* __restrict__ metric) {
    int i = blockIdx.x * 256 + threadIdx.x;  // 0..2047
    int n = i & 1023;
    float v = base_metric[n] + 0.1f * mod[i];
    float sp = fmaxf(v, 0.f) + log1pf(expf(-fabsf(v)));
    metric[i] = sp + 1e-6f;
}

// ---------------- causal K-window + hebbian + gating ----------------
__global__ __launch_bounds__(64) void window_kernel(
    const float* __restrict__ qs, const float* __restrict__ vs,
    const float* __restrict__ metric, const float* __restrict__ heb,
    float* __restrict__ gated) {
    int idx = blockIdx.x;               // (b*T+t)*H + h
    int h = idx & (H_ - 1);
    int bt = idx >> 3;
    int t = bt & (T_ - 1);
    int b = bt >> 10;
    int lane = threadIdx.x;
    long rowbase = ((long)bt * N_) + h * HD_;
    float q0 = qs[rowbase + lane];
    float q1 = qs[rowbase + lane + 64];
    float m0 = metric[(b * H_ + h) * HD_ + lane];
    float m1 = metric[(b * H_ + h) * HD_ + lane + 64];
    float infl[K_];
    float wsum = 0.f;
    #pragma unroll 4
    for (int k = 0; k < K_; ++k) {
        int src = t - (K_ - 1) + k;
        float qw0 = 0.f, qw1 = 0.f;
        if (src >= 0) {
            long rb = ((long)(b * T_ + src) * N_) + h * HD_;
            qw0 = qs[rb + lane]; qw1 = qs[rb + lane + 64];
        }
        float d0 = q0 - qw0, d1 = q1 - qw1;
        float val = m0 * d0 * d0 + m1 * d1 * d1;
        #pragma unroll
        for (int off = 32; off; off >>= 1) val += __shfl_xor(val, off);
        float w = expf(-sqrtf(val + 1e-8f));
        infl[k] = w;
        wsum += w;                       // padded positions DO contribute (matches ref)
    }
    float inv = 1.0f / (wsum + 1e-8f);
    float c0 = 0.f, c1 = 0.f;
    #pragma unroll 4
    for (int k = 0; k < K_; ++k) {
        int src = t - (K_ - 1) + k;
        if (src < 0) continue;           // vw is zero there
        long rb = ((long)(b * T_ + src) * N_) + h * HD_;
        float w = infl[k] * inv;
        c0 = fmaf(w, vs[rb + lane], c0);
        c1 = fmaf(w, vs[rb + lane + 64], c1);
    }
    // qn = qs / max(||qs||, 1e-12)
    float nv = q0 * q0 + q1 * q1;
    #pragma unroll
    for (int off = 32; off; off >>= 1) nv += __shfl_xor(nv, off);
    float invn = 1.0f / fmaxf(sqrtf(nv), 1e-12f);
    const float* hb = heb + (long)h * HD_ * HD_;
    #pragma unroll 4
    for (int dd = 0; dd < HD_; ++dd) {
        float qd = ((dd < 64) ? __shfl(q0, dd) : __shfl(q1, dd - 64)) * invn;
        c0 = fmaf(qd, hb[dd * HD_ + lane], c0);
        c1 = fmaf(qd, hb[dd * HD_ + lane + 64], c1);
    }
    gated[rowbase + lane] = q0 * c0;
    gated[rowbase + lane + 64] = q1 * c1;
}

// ---------------- x += a + b ----------------
__global__ void add3_kernel(float* __restrict__ x, const float* __restrict__ a,
                            const float* __restrict__ b, int n) {
    int i = blockIdx.x * 256 + threadIdx.x;
    if (i < n) x[i] += a[i] + b[i];
}

extern "C" void kernel_launch(void* const* d_in, const int* in_sizes, int n_in,
                              void* d_out, int out_size, void* d_ws, size_t ws_size,
                              hipStream_t stream) {
    const int*   tokens      = (const int*)  d_in[0];
    const float* emb         = (const float*)d_in[1];
    const float* field_init  = (const float*)d_in[2];
    const float* Wq          = (const float*)d_in[3];
    const float* Wv          = (const float*)d_in[4];
    const float* mW1         = (const float*)d_in[5];
    const float* mb1         = (const float*)d_in[6];
    const float* mW2         = (const float*)d_in[7];
    const float* mb2         = (const float*)d_in[8];
    const float* base_metric = (const float*)d_in[9];
    const float* decoder     = (const float*)d_in[10];
    const float* hebbian     = (const float*)d_in[11];
    const float* fW1         = (const float*)d_in[12];
    const float* fb1         = (const float*)d_in[13];
    const float* fW2         = (const float*)d_in[14];
    const float* fb2         = (const float*)d_in[15];
    const float* g1          = (const float*)d_in[16];
    const float* b1          = (const float*)d_in[17];
    const float* g2          = (const float*)d_in[18];
    const float* b2          = (const float*)d_in[19];
    const float* gf          = (const float*)d_in[20];
    const float* bf          = (const float*)d_in[21];
    const float* Wl          = (const float*)d_in[22];
    const float* bl          = (const float*)d_in[23];
    float* out = (float*)d_out;

    float* w = (float*)d_ws;
    float* x       = w; w += 524288;          // B*T*D
    float* y1      = w; w += 524288;
    float* y2      = w; w += 524288;
    float* yf      = w; w += 524288;
    float* dec_out = w; w += 524288;
    float* ffn_out = w; w += 524288;
    float* qs      = w; w += 2097152;         // B*T*N
    float* vs      = w; w += 2097152;
    float* gated   = w; w += 2097152;
    float* ffn_hid = w; w += 2097152;         // B*T*4D
    float* ps      = w; w += TC_ * 2048;
    float* ps8     = w; w += TC_ * 2048;
    float* sigb    = w; w += 2048;            // B*N
    float* hidm    = w; w += 1024;            // B*512
    float* modb    = w; w += 2048;            // B*N
    float* metricb = w; w += 2048;            // B*H*HD

    embed_rope_kernel<<<B_ * T_, 256, 0, stream>>>(tokens, emb, field_init, x);

    for (int step = 0; step < 2; ++step) {
        ln_dual_kernel<<<B_ * T_, 256, 0, stream>>>(x, g1, b1, g2, b2, y1, y2);
        // qs = relu(y1 @ Wq[h]) ; vs = relu(y1 @ Wv[h])   (batched over h)
        gemm_kernel<1><<<dim3(2, 32, 8), 256, 0, stream>>>(
            y1, D_, 0L, Wq, HD_, (long)D_ * HD_, nullptr, qs, N_, (long)HD_,
            B_ * T_, HD_, D_);
        gemm_kernel<1><<<dim3(2, 32, 8), 256, 0, stream>>>(
            y1, D_, 0L, Wv, HD_, (long)D_ * HD_, nullptr, vs, N_, (long)HD_,
            B_ * T_, HD_, D_);
        // sig
        sig_stage1<<<dim3(8, TC_), 256, 0, stream>>>(qs, ps, ps8);
        sig_stage2<<<8, 256, 0, stream>>>(ps, ps8, sigb);
        // metric MLP
        gemm_kernel<2><<<dim3(8, 1), 256, 0, stream>>>(
            sigb, N_, 0L, mW1, 512, 0L, mb1, hidm, 512, 0L, B_, 512, N_);
        gemm_kernel<0><<<dim3(16, 1), 256, 0, stream>>>(
            hidm, 512, 0L, mW2, N_, 0L, mb2, modb, N_, 0L, B_, N_, 512);
        metric_kernel<<<8, 256, 0, stream>>>(base_metric, modb, metricb);
        // window attention + hebbian + gate
        window_kernel<<<B_ * T_ * H_, 64, 0, stream>>>(qs, vs, metricb, hebbian, gated);
        // decode
        gemm_kernel<0><<<dim3(4, 32), 256, 0, stream>>>(
            gated, N_, 0L, decoder, D_, 0L, nullptr, dec_out, D_, 0L, B_ * T_, D_, N_);
        // FFN
        gemm_kernel<2><<<dim3(16, 32), 256, 0, stream>>>(
            y2, D_, 0L, fW1, 4 * D_, 0L, fb1, ffn_hid, 4 * D_, 0L, B_ * T_, 4 * D_, D_);
        gemm_kernel<0><<<dim3(4, 32), 256, 0, stream>>>(
            ffn_hid, 4 * D_, 0L, fW2, D_, 0L, fb2, ffn_out, D_, 0L, B_ * T_, D_, 4 * D_);
        // x = x + dx
        add3_kernel<<<2048, 256, 0, stream>>>(x, dec_out, ffn_out, B_ * T_ * D_);
    }
    // final LN + vocab projection
    ln_dual_kernel<<<B_ * T_, 256, 0, stream>>>(x, gf, bf, nullptr, nullptr, yf, nullptr);
    gemm_kernel<0><<<dim3(500, 32), 256, 0, stream>>>(
        yf, D_, 0L, Wl, VOCAB_, 0L, bl, out, VOCAB_, 0L, B_ * T_, VOCAB_, D_);
}

// Round 2
// 703.882 us; speedup vs baseline: 1.7362x; 1.7362x over previous
//
#include <hip/hip_runtime.h>
#include <hip/hip_bf16.h>
#include <math.h>

#define B_ 2
#define T_ 1024
#define D_ 256
#define N_ 1024
#define H_ 8
#define HD_ 128
#define K_ 32
#define VOCAB_ 32000
#define TC_ 16

typedef __attribute__((ext_vector_type(8))) short short8v;
typedef __attribute__((ext_vector_type(4))) float f32x4;

static __device__ __forceinline__ float geluf(float x) {
    return 0.5f * x * (1.0f + erff(x * 0.70710678118654752f));
}

static __device__ __forceinline__ ushort f2bf(float f) {
    unsigned u = __builtin_bit_cast(unsigned, f);
    u += 0x7fff + ((u >> 16) & 1);
    return (ushort)(u >> 16);
}

// ---------------- embed + quantized RoPE ----------------
__global__ void embed_rope_kernel(const int* __restrict__ tokens,
                                  const float* __restrict__ emb,
                                  const float* __restrict__ field_init,
                                  float* __restrict__ x) {
    int bt = blockIdx.x;          // b*T + t
    int d = threadIdx.x;          // 0..255
    int t = bt & (T_ - 1);
    int tok = tokens[bt];
    float v = emb[(long)tok * D_ + d] + field_init[d];
    float partner = __shfl_xor(v, 1);
    float rot = (d & 1) ? partner : -partner;
    float freq = exp2f(-0.0625f * (float)(d & ~1)) * (1.0f / 6.283185307179586f);
    float ph = fmodf((float)t * freq, 1.0f) * 6.283185307179586f;
    x[(long)bt * D_ + d] = v * cosf(ph) + rot * sinf(ph);
}

// ---------------- dual LayerNorm (shared mean/var) -> bf16 outputs ----------------
__global__ void ln_dual_kernel(const float* __restrict__ x,
                               const float* __restrict__ g1, const float* __restrict__ b1,
                               const float* __restrict__ g2, const float* __restrict__ b2,
                               ushort* __restrict__ y1, ushort* __restrict__ y2) {
    int row = blockIdx.x;
    int d = threadIdx.x;
    float v = x[(long)row * D_ + d];
    __shared__ float red[4];
    int lane = d & 63, wid = d >> 6;
    float s = v;
    #pragma unroll
    for (int off = 32; off; off >>= 1) s += __shfl_xor(s, off);
    if (lane == 0) red[wid] = s;
    __syncthreads();
    float mu = (red[0] + red[1] + red[2] + red[3]) * (1.0f / D_);
    float dv = v - mu;
    float s2 = dv * dv;
    #pragma unroll
    for (int off = 32; off; off >>= 1) s2 += __shfl_xor(s2, off);
    __syncthreads();
    if (lane == 0) red[wid] = s2;
    __syncthreads();
    float var = (red[0] + red[1] + red[2] + red[3]) * (1.0f / D_);
    float rstd = rsqrtf(var + 1e-5f);
    float nv = dv * rstd;
    y1[(long)row * D_ + d] = f2bf(nv * g1[d] + b1[d]);
    if (y2) y2[(long)row * D_ + d] = f2bf(nv * g2[d] + b2[d]);
}

// ---------------- transpose-cast: in f32 [R][C] -> out bf16 [C][R] ----------------
__global__ __launch_bounds__(256) void tcast_kernel(
    const float* __restrict__ in, ushort* __restrict__ out,
    int R, int C, long inStride, long outStride) {
    in += (long)blockIdx.z * inStride;
    out += (long)blockIdx.z * outStride;
    __shared__ float sm[64][65];
    int r0 = blockIdx.y * 64, c0 = blockIdx.x * 64;
    int tx = threadIdx.x & 63, ty = threadIdx.x >> 6;
    #pragma unroll
    for (int i = 0; i < 16; ++i) {
        int r = i * 4 + ty;
        sm[r][tx] = in[(long)(r0 + r) * C + c0 + tx];
    }
    __syncthreads();
    #pragma unroll
    for (int i = 0; i < 16; ++i) {
        int c = i * 4 + ty;
        out[(long)(c0 + c) * R + r0 + tx] = f2bf(sm[tx][c]);
    }
}

// ---------------- bf16 MFMA GEMM: C = act(A @ Bt^T + bias) ----------------
// A: [M][K] bf16 k-major; Bt: [N][K] bf16 k-major; M%128==0, N%128==0, K%32==0
#define LDK 40

template<int ACT, int OUTBF>  // ACT: 0 none, 1 relu, 2 gelu
__global__ __launch_bounds__(256) void mfma_gemm_bt(
    const ushort* __restrict__ A, const ushort* __restrict__ Bt,
    const float* __restrict__ bias, void* __restrict__ Cout,
    int M, int N, int K) {
    __shared__ __align__(16) ushort As[128 * LDK];
    __shared__ __align__(16) ushort Bs[128 * LDK];
    int tid = threadIdx.x;
    int wid = tid >> 6, lane = tid & 63;
    int brow = blockIdx.y * 128, bcol = blockIdx.x * 128;
    int wr = wid >> 1, wc = wid & 1;     // 2x2 waves, 64x64 each
    f32x4 acc[4][4] = {};
    for (int k0 = 0; k0 < K; k0 += 32) {
        __syncthreads();
        #pragma unroll
        for (int j = 0; j < 2; ++j) {
            int idx = tid + j * 256;
            int r = idx >> 2, sgm = idx & 3;
            *(short8v*)&As[r * LDK + sgm * 8] =
                *(const short8v*)&A[(long)(brow + r) * K + k0 + sgm * 8];
            *(short8v*)&Bs[r * LDK + sgm * 8] =
                *(const short8v*)&Bt[(long)(bcol + r) * K + k0 + sgm * 8];
        }
        __syncthreads();
        short8v af[4], bfv[4];
        #pragma unroll
        for (int m = 0; m < 4; ++m)
            af[m] = *(const short8v*)&As[(wr * 64 + m * 16 + (lane & 15)) * LDK + (lane >> 4) * 8];
        #pragma unroll
        for (int n = 0; n < 4; ++n)
            bfv[n] = *(const short8v*)&Bs[(wc * 64 + n * 16 + (lane & 15)) * LDK + (lane >> 4) * 8];
        #pragma unroll
        for (int m = 0; m < 4; ++m)
            #pragma unroll
            for (int n = 0; n < 4; ++n)
                acc[m][n] = __builtin_amdgcn_mfma_f32_16x16x32_bf16(af[m], bfv[n], acc[m][n], 0, 0, 0);
    }
    int r0 = brow + wr * 64 + ((lane >> 4) << 2);
    int c0 = bcol + wc * 64 + (lane & 15);
    #pragma unroll
    for (int n = 0; n < 4; ++n) {
        int col = c0 + n * 16;
        float bv = bias ? bias[col] : 0.0f;
        #pragma unroll
        for (int m = 0; m < 4; ++m) {
            #pragma unroll
            for (int j = 0; j < 4; ++j) {
                float v = acc[m][n][j] + bv;
                if (ACT == 1) v = fmaxf(v, 0.0f);
                if (ACT == 2) v = geluf(v);
                long off = (long)(r0 + m * 16 + j) * N + col;
                if (OUTBF) ((ushort*)Cout)[off] = f2bf(v);
                else       ((float*)Cout)[off] = v;
            }
        }
    }
}

// ---------------- sig reduction (two stage) ----------------
__global__ void sig_stage1(const float* __restrict__ qs,
                           float* __restrict__ ps, float* __restrict__ ps8) {
    int bn = blockIdx.x * 256 + threadIdx.x;  // 0..2047  (b*1024+n)
    int tc = blockIdx.y;
    int b = bn >> 10, n = bn & 1023;
    float s = 0.f, s8 = 0.f;
    int t0 = tc * (T_ / TC_);
    for (int t = t0; t < t0 + T_ / TC_; ++t) {
        float v = qs[((long)(b * T_ + t) << 10) + n];
        s += v;
        if ((t & 7) == 0) s8 += v;
    }
    ps[tc * 2048 + bn] = s;
    ps8[tc * 2048 + bn] = s8;
}

__global__ void sig_stage2(const float* __restrict__ ps, const float* __restrict__ ps8,
                           float* __restrict__ sig) {
    int bn = blockIdx.x * 256 + threadIdx.x;
    float s = 0.f, s8 = 0.f;
    for (int tc = 0; tc < TC_; ++tc) { s += ps[tc * 2048 + bn]; s8 += ps8[tc * 2048 + bn]; }
    sig[bn] = s * (1.0f / T_) + 0.5f * s8 * (1.0f / (T_ / 8));
}

// ---------------- generic tiled f32 GEMM (small metric MLP only) ----------------
#define BM 64
#define BN 64
#define BK 16

template<int ACT>
__global__ __launch_bounds__(256) void gemm_kernel(
    const float* __restrict__ A, int lda,
    const float* __restrict__ Bm, int ldb,
    const float* __restrict__ bias,
    float* __restrict__ C, int ldc,
    int M, int N, int Kd) {
    __shared__ float As[BK][BM];
    __shared__ float Bs[BK][BN];
    int tid = threadIdx.x;
    int row0 = blockIdx.y * BM, col0 = blockIdx.x * BN;
    int am = tid >> 2, ak = (tid & 3) << 2;
    int bk = tid >> 4, bn = (tid & 15) << 2;
    int ty = tid >> 4, tx = tid & 15;
    float acc[4][4] = {};
    for (int k0 = 0; k0 < Kd; k0 += BK) {
        float4 av = make_float4(0.f, 0.f, 0.f, 0.f);
        if (row0 + am < M)
            av = *(const float4*)(A + (long)(row0 + am) * lda + k0 + ak);
        float4 bv = *(const float4*)(Bm + (long)(k0 + bk) * ldb + col0 + bn);
        __syncthreads();
        As[ak + 0][am] = av.x; As[ak + 1][am] = av.y;
        As[ak + 2][am] = av.z; As[ak + 3][am] = av.w;
        *(float4*)&Bs[bk][bn] = bv;
        __syncthreads();
        #pragma unroll
        for (int kk = 0; kk < BK; ++kk) {
            float4 a4 = *(const float4*)&As[kk][ty << 2];
            float4 b4 = *(const float4*)&Bs[kk][tx << 2];
            float a[4] = {a4.x, a4.y, a4.z, a4.w};
            float b[4] = {b4.x, b4.y, b4.z, b4.w};
            #pragma unroll
            for (int i = 0; i < 4; ++i)
                #pragma unroll
                for (int j = 0; j < 4; ++j)
                    acc[i][j] = fmaf(a[i], b[j], acc[i][j]);
        }
    }
    #pragma unroll
    for (int i = 0; i < 4; ++i) {
        int row = row0 + (ty << 2) + i;
        if (row >= M) break;
        #pragma unroll
        for (int j = 0; j < 4; ++j) {
            int col = col0 + (tx << 2) + j;
            float v = acc[i][j] + (bias ? bias[col] : 0.0f);
            if (ACT == 1) v = fmaxf(v, 0.0f);
            if (ACT == 2) v = geluf(v);
            C[(long)row * ldc + col] = v;
        }
    }
}

// ---------------- metric = softplus(base + 0.1*mod) + 1e-6 ----------------
__global__ void metric_kernel(const float* __restrict__ base_metric,
                              const float* __restrict__ mod, float* __restrict__ metric) {
    int i = blockIdx.x * 256 + threadIdx.x;  // 0..2047
    int n = i & 1023;
    float v = base_metric[n] + 0.1f * mod[i];
    float sp = fmaxf(v, 0.f) + log1pf(expf(-fabsf(v)));
    metric[i] = sp + 1e-6f;
}

// ---------------- causal K-window + hebbian + gating (bf16 out) ----------------
__global__ __launch_bounds__(64) void window_kernel(
    const float* __restrict__ qs, const float* __restrict__ vs,
    const float* __restrict__ metric, const float* __restrict__ heb,
    ushort* __restrict__ gated) {
    int idx = blockIdx.x;               // (b*T+t)*H + h
    int h = idx & (H_ - 1);
    int bt = idx >> 3;
    int t = bt & (T_ - 1);
    int b = bt >> 10;
    int lane = threadIdx.x;
    long rowbase = ((long)bt * N_) + h * HD_;
    float q0 = qs[rowbase + lane];
    float q1 = qs[rowbase + lane + 64];
    float m0 = metric[(b * H_ + h) * HD_ + lane];
    float m1 = metric[(b * H_ + h) * HD_ + lane + 64];
    float infl[K_];
    float wsum = 0.f;
    #pragma unroll 4
    for (int k = 0; k < K_; ++k) {
        int src = t - (K_ - 1) + k;
        float qw0 = 0.f, qw1 = 0.f;
        if (src >= 0) {
            long rb = ((long)(b * T_ + src) * N_) + h * HD_;
            qw0 = qs[rb + lane]; qw1 = qs[rb + lane + 64];
        }
        float d0 = q0 - qw0, d1 = q1 - qw1;
        float val = m0 * d0 * d0 + m1 * d1 * d1;
        #pragma unroll
        for (int off = 32; off; off >>= 1) val += __shfl_xor(val, off);
        float w = expf(-sqrtf(val + 1e-8f));
        infl[k] = w;
        wsum += w;                       // padded positions DO contribute (matches ref)
    }
    float inv = 1.0f / (wsum + 1e-8f);
    float c0 = 0.f, c1 = 0.f;
    #pragma unroll 4
    for (int k = 0; k < K_; ++k) {
        int src = t - (K_ - 1) + k;
        if (src < 0) continue;           // vw is zero there
        long rb = ((long)(b * T_ + src) * N_) + h * HD_;
        float w = infl[k] * inv;
        c0 = fmaf(w, vs[rb + lane], c0);
        c1 = fmaf(w, vs[rb + lane + 64], c1);
    }
    float nv = q0 * q0 + q1 * q1;
    #pragma unroll
    for (int off = 32; off; off >>= 1) nv += __shfl_xor(nv, off);
    float invn = 1.0f / fmaxf(sqrtf(nv), 1e-12f);
    const float* hb = heb + (long)h * HD_ * HD_;
    #pragma unroll 4
    for (int dd = 0; dd < HD_; ++dd) {
        float qd = ((dd < 64) ? __shfl(q0, dd) : __shfl(q1, dd - 64)) * invn;
        c0 = fmaf(qd, hb[dd * HD_ + lane], c0);
        c1 = fmaf(qd, hb[dd * HD_ + lane + 64], c1);
    }
    gated[rowbase + lane] = f2bf(q0 * c0);
    gated[rowbase + lane + 64] = f2bf(q1 * c1);
}

// ---------------- x += a + b ----------------
__global__ void add3_kernel(float* __restrict__ x, const float* __restrict__ a,
                            const float* __restrict__ b, int n) {
    int i = blockIdx.x * 256 + threadIdx.x;
    if (i < n) x[i] += a[i] + b[i];
}

extern "C" void kernel_launch(void* const* d_in, const int* in_sizes, int n_in,
                              void* d_out, int out_size, void* d_ws, size_t ws_size,
                              hipStream_t stream) {
    const int*   tokens      = (const int*)  d_in[0];
    const float* emb         = (const float*)d_in[1];
    const float* field_init  = (const float*)d_in[2];
    const float* Wq          = (const float*)d_in[3];
    const float* Wv          = (const float*)d_in[4];
    const float* mW1         = (const float*)d_in[5];
    const float* mb1         = (const float*)d_in[6];
    const float* mW2         = (const float*)d_in[7];
    const float* mb2         = (const float*)d_in[8];
    const float* base_metric = (const float*)d_in[9];
    const float* decoder     = (const float*)d_in[10];
    const float* hebbian     = (const float*)d_in[11];
    const float* fW1         = (const float*)d_in[12];
    const float* fb1         = (const float*)d_in[13];
    const float* fW2         = (const float*)d_in[14];
    const float* fb2         = (const float*)d_in[15];
    const float* g1          = (const float*)d_in[16];
    const float* b1          = (const float*)d_in[17];
    const float* g2          = (const float*)d_in[18];
    const float* b2          = (const float*)d_in[19];
    const float* gf          = (const float*)d_in[20];
    const float* bf          = (const float*)d_in[21];
    const float* Wl          = (const float*)d_in[22];
    const float* bl          = (const float*)d_in[23];
    float* out = (float*)d_out;

    char* wp = (char*)d_ws;
    auto alloc = [&](size_t bytes) { char* p = wp; wp += (bytes + 255) & ~255UL; return p; };
    float*  x        = (float*) alloc(524288 * 4);
    ushort* y1_bf    = (ushort*)alloc(524288 * 2);
    ushort* y2_bf    = (ushort*)alloc(524288 * 2);
    ushort* yf_bf    = (ushort*)alloc(524288 * 2);
    float*  qs       = (float*) alloc(2097152 * 4);   // } WlT_bf aliases qs+vs (16MB)
    float*  vs       = (float*) alloc(2097152 * 4);   // }
    ushort* gated_bf = (ushort*)alloc(2097152 * 2);
    ushort* ffnh_bf  = (ushort*)alloc(2097152 * 2);
    float*  dec_out  = (float*) alloc(524288 * 4);
    float*  ffn_out  = (float*) alloc(524288 * 4);
    ushort* WqT      = (ushort*)alloc(262144 * 2);
    ushort* WvT      = (ushort*)alloc(262144 * 2);
    ushort* decT     = (ushort*)alloc(262144 * 2);
    ushort* fW1T     = (ushort*)alloc(262144 * 2);
    ushort* fW2T     = (ushort*)alloc(262144 * 2);
    float*  ps       = (float*) alloc(TC_ * 2048 * 4);
    float*  ps8      = (float*) alloc(TC_ * 2048 * 4);
    float*  sigb     = (float*) alloc(2048 * 4);
    float*  hidm     = (float*) alloc(1024 * 4);
    float*  modb     = (float*) alloc(2048 * 4);
    float*  metricb  = (float*) alloc(2048 * 4);
    ushort* WlT      = (ushort*)qs;                   // 32000*256*2 = 16MB over qs+vs

    // weight transpose-casts (f32 [R][C] -> bf16 [C][R])
    tcast_kernel<<<dim3(2, 4, 8), 256, 0, stream>>>(Wq, WqT, 256, 128, 256 * 128, 128 * 256);
    tcast_kernel<<<dim3(2, 4, 8), 256, 0, stream>>>(Wv, WvT, 256, 128, 256 * 128, 128 * 256);
    tcast_kernel<<<dim3(4, 16, 1), 256, 0, stream>>>(decoder, decT, 1024, 256, 0, 0);
    tcast_kernel<<<dim3(16, 4, 1), 256, 0, stream>>>(fW1, fW1T, 256, 1024, 0, 0);
    tcast_kernel<<<dim3(4, 16, 1), 256, 0, stream>>>(fW2, fW2T, 1024, 256, 0, 0);

    embed_rope_kernel<<<B_ * T_, 256, 0, stream>>>(tokens, emb, field_init, x);

    for (int step = 0; step < 2; ++step) {
        ln_dual_kernel<<<B_ * T_, 256, 0, stream>>>(x, g1, b1, g2, b2, y1_bf, y2_bf);
        // qs/vs = relu(y1 @ W{q,v}) as single N=1024 MFMA GEMMs
        mfma_gemm_bt<1, 0><<<dim3(8, 16), 256, 0, stream>>>(y1_bf, WqT, nullptr, qs, 2048, 1024, 256);
        mfma_gemm_bt<1, 0><<<dim3(8, 16), 256, 0, stream>>>(y1_bf, WvT, nullptr, vs, 2048, 1024, 256);
        // sig
        sig_stage1<<<dim3(8, TC_), 256, 0, stream>>>(qs, ps, ps8);
        sig_stage2<<<8, 256, 0, stream>>>(ps, ps8, sigb);
        // metric MLP (tiny, f32)
        gemm_kernel<2><<<dim3(8, 1), 256, 0, stream>>>(sigb, N_, mW1, 512, mb1, hidm, 512, B_, 512, N_);
        gemm_kernel<0><<<dim3(16, 1), 256, 0, stream>>>(hidm, 512, mW2, N_, mb2, modb, N_, B_, N_, 512);
        metric_kernel<<<8, 256, 0, stream>>>(base_metric, modb, metricb);
        // window attention + hebbian + gate
        window_kernel<<<B_ * T_ * H_, 64, 0, stream>>>(qs, vs, metricb, hebbian, gated_bf);
        // decode
        mfma_gemm_bt<0, 0><<<dim3(2, 16), 256, 0, stream>>>(gated_bf, decT, nullptr, dec_out, 2048, 256, 1024);
        // FFN
        mfma_gemm_bt<2, 1><<<dim3(8, 16), 256, 0, stream>>>(y2_bf, fW1T, fb1, ffnh_bf, 2048, 1024, 256);
        mfma_gemm_bt<0, 0><<<dim3(2, 16), 256, 0, stream>>>(ffnh_bf, fW2T, fb2, ffn_out, 2048, 256, 1024);
        // x = x + dx
        add3_kernel<<<2048, 256, 0, stream>>>(x, dec_out, ffn_out, B_ * T_ * D_);
    }
    // final LN + vocab projection (Wl transpose-cast into dead qs/vs space)
    ln_dual_kernel<<<B_ * T_, 256, 0, stream>>>(x, gf, bf, nullptr, nullptr, yf_bf, nullptr);
    tcast_kernel<<<dim3(500, 4, 1), 256, 0, stream>>>(Wl, WlT, 256, VOCAB_, 0, 0);
    mfma_gemm_bt<0, 0><<<dim3(250, 16), 256, 0, stream>>>(yf_bf, WlT, bl, out, 2048, VOCAB_, 256);
}

// Round 3
// 500.078 us; speedup vs baseline: 2.4438x; 1.4075x over previous
//
#include <hip/hip_runtime.h>
#include <hip/hip_bf16.h>
#include <math.h>

#define B_ 2
#define T_ 1024
#define D_ 256
#define N_ 1024
#define H_ 8
#define HD_ 128
#define K_ 32
#define VOCAB_ 32000
#define TC_ 16

typedef __attribute__((ext_vector_type(8))) short short8v;
typedef __attribute__((ext_vector_type(4))) float f32x4;

static __device__ __forceinline__ float geluf(float x) {
    return 0.5f * x * (1.0f + erff(x * 0.70710678118654752f));
}

static __device__ __forceinline__ ushort f2bf(float f) {
    unsigned u = __builtin_bit_cast(unsigned, f);
    u += 0x7fff + ((u >> 16) & 1);
    return (ushort)(u >> 16);
}

static __device__ __forceinline__ float bf2f(ushort u) {
    unsigned v = ((unsigned)u) << 16;
    return __builtin_bit_cast(float, v);
}

// ---------------- embed + quantized RoPE ----------------
__global__ void embed_rope_kernel(const int* __restrict__ tokens,
                                  const float* __restrict__ emb,
                                  const float* __restrict__ field_init,
                                  float* __restrict__ x) {
    int bt = blockIdx.x;
    int d = threadIdx.x;
    int t = bt & (T_ - 1);
    int tok = tokens[bt];
    float v = emb[(long)tok * D_ + d] + field_init[d];
    float partner = __shfl_xor(v, 1);
    float rot = (d & 1) ? partner : -partner;
    float freq = exp2f(-0.0625f * (float)(d & ~1)) * (1.0f / 6.283185307179586f);
    float ph = fmodf((float)t * freq, 1.0f) * 6.283185307179586f;
    x[(long)bt * D_ + d] = v * cosf(ph) + rot * sinf(ph);
}

// ---------------- LayerNorm (+ optional residual add) -> bf16 outputs ----------------
__global__ void ln_kernel(float* __restrict__ x,
                          const float* __restrict__ addA, const float* __restrict__ addB,
                          const float* __restrict__ g1, const float* __restrict__ b1,
                          const float* __restrict__ g2, const float* __restrict__ b2,
                          ushort* __restrict__ y1, ushort* __restrict__ y2) {
    int row = blockIdx.x;
    int d = threadIdx.x;
    long i = (long)row * D_ + d;
    float v = x[i];
    if (addA) { v += addA[i] + addB[i]; x[i] = v; }
    __shared__ float red[4];
    int lane = d & 63, wid = d >> 6;
    float s = v;
    #pragma unroll
    for (int off = 32; off; off >>= 1) s += __shfl_xor(s, off);
    if (lane == 0) red[wid] = s;
    __syncthreads();
    float mu = (red[0] + red[1] + red[2] + red[3]) * (1.0f / D_);
    float dv = v - mu;
    float s2 = dv * dv;
    #pragma unroll
    for (int off = 32; off; off >>= 1) s2 += __shfl_xor(s2, off);
    __syncthreads();
    if (lane == 0) red[wid] = s2;
    __syncthreads();
    float var = (red[0] + red[1] + red[2] + red[3]) * (1.0f / D_);
    float rstd = rsqrtf(var + 1e-5f);
    float nv = dv * rstd;
    y1[i] = f2bf(nv * g1[d] + b1[d]);
    if (y2) y2[i] = f2bf(nv * g2[d] + b2[d]);
}

// ---------------- transpose-cast: in f32 [R][C] -> out bf16 [C][R] ----------------
__global__ __launch_bounds__(256) void tcast_kernel(
    const float* __restrict__ in, ushort* __restrict__ out,
    int R, int C, long inStride, long outStride) {
    in += (long)blockIdx.z * inStride;
    out += (long)blockIdx.z * outStride;
    __shared__ float sm[64][65];
    int r0 = blockIdx.y * 64, c0 = blockIdx.x * 64;
    int tx = threadIdx.x & 63, ty = threadIdx.x >> 6;
    #pragma unroll
    for (int i = 0; i < 16; ++i) {
        int r = i * 4 + ty;
        sm[r][tx] = in[(long)(r0 + r) * C + c0 + tx];
    }
    __syncthreads();
    #pragma unroll
    for (int i = 0; i < 16; ++i) {
        int c = i * 4 + ty;
        out[(long)(c0 + c) * R + r0 + tx] = f2bf(sm[tx][c]);
    }
}

// ================= 128x128 MFMA core, BK=64 (LDK=72: 2-way banks, free) =============
#define LDK 72

__device__ __forceinline__ void gemm128_core(
    const ushort* __restrict__ A, const ushort* __restrict__ Bt,
    const float* __restrict__ bias, void* __restrict__ Cout,
    int N, int Kd, int bx, int by, int act, int outbf) {
    __shared__ __align__(16) ushort As[128 * LDK];
    __shared__ __align__(16) ushort Bs[128 * LDK];
    int tid = threadIdx.x;
    int wid = tid >> 6, lane = tid & 63;
    int brow = by * 128, bcol = bx * 128;
    int wr = wid >> 1, wc = wid & 1;
    f32x4 acc[4][4] = {};
    for (int k0 = 0; k0 < Kd; k0 += 64) {
        __syncthreads();
        #pragma unroll
        for (int j = 0; j < 4; ++j) {
            int idx = tid + j * 256;
            int r = idx >> 3, sgm = idx & 7;
            *(short8v*)&As[r * LDK + sgm * 8] =
                *(const short8v*)&A[(long)(brow + r) * Kd + k0 + sgm * 8];
            *(short8v*)&Bs[r * LDK + sgm * 8] =
                *(const short8v*)&Bt[(long)(bcol + r) * Kd + k0 + sgm * 8];
        }
        __syncthreads();
        #pragma unroll
        for (int kk = 0; kk < 2; ++kk) {
            short8v af[4], bfv[4];
            #pragma unroll
            for (int m = 0; m < 4; ++m)
                af[m] = *(const short8v*)&As[(wr * 64 + m * 16 + (lane & 15)) * LDK + kk * 32 + (lane >> 4) * 8];
            #pragma unroll
            for (int n = 0; n < 4; ++n)
                bfv[n] = *(const short8v*)&Bs[(wc * 64 + n * 16 + (lane & 15)) * LDK + kk * 32 + (lane >> 4) * 8];
            #pragma unroll
            for (int m = 0; m < 4; ++m)
                #pragma unroll
                for (int n = 0; n < 4; ++n)
                    acc[m][n] = __builtin_amdgcn_mfma_f32_16x16x32_bf16(af[m], bfv[n], acc[m][n], 0, 0, 0);
        }
    }
    int r0 = brow + wr * 64 + ((lane >> 4) << 2);
    int c0 = bcol + wc * 64 + (lane & 15);
    #pragma unroll
    for (int n = 0; n < 4; ++n) {
        int col = c0 + n * 16;
        float bv = bias ? bias[col] : 0.0f;
        #pragma unroll
        for (int m = 0; m < 4; ++m) {
            #pragma unroll
            for (int j = 0; j < 4; ++j) {
                float v = acc[m][n][j] + bv;
                if (act == 1) v = fmaxf(v, 0.0f);
                else if (act == 2) v = geluf(v);
                long off = (long)(r0 + m * 16 + j) * N + col;
                if (outbf) ((ushort*)Cout)[off] = f2bf(v);
                else       ((float*)Cout)[off] = v;
            }
        }
    }
}

// batched qs/vs/ffn1:  z=0: qs=relu(y1@WqT^T) f32; z=1: vs=relu(y1@WvT^T) f32; z=2: ffnh=gelu(y2@fW1T^T+fb1) bf16
__global__ __launch_bounds__(256) void gemm3_kernel(
    const ushort* __restrict__ y1, const ushort* __restrict__ y2,
    const ushort* __restrict__ WqT, const ushort* __restrict__ WvT, const ushort* __restrict__ fW1T,
    const float* __restrict__ fb1,
    float* __restrict__ qs, float* __restrict__ vs, ushort* __restrict__ ffnh) {
    int z = blockIdx.z;
    const ushort* A = (z == 2) ? y2 : y1;
    const ushort* Bt = (z == 0) ? WqT : (z == 1) ? WvT : fW1T;
    const float* bias = (z == 2) ? fb1 : nullptr;
    void* C = (z == 0) ? (void*)qs : (z == 1) ? (void*)vs : (void*)ffnh;
    gemm128_core(A, Bt, bias, C, 1024, 256, blockIdx.x, blockIdx.y, (z == 2) ? 2 : 1, (z == 2) ? 1 : 0);
}

// vocab projection with XCD-chunked block swizzle (grid 4000 = 8*500)
__global__ __launch_bounds__(256) void vocab_kernel(
    const ushort* __restrict__ yf, const ushort* __restrict__ WlT,
    const float* __restrict__ bl, float* __restrict__ out) {
    int g = blockIdx.x;
    int nid = (g & 7) * 500 + (g >> 3);
    gemm128_core(yf, WlT, bl, out, VOCAB_, 256, nid >> 4, nid & 15, 0, 0);
}

// ================= 64x64 MFMA core for N=256 GEMMs (decoder + FFN2) =============
__global__ __launch_bounds__(256) void gemm2_kernel(
    const ushort* __restrict__ gated, const ushort* __restrict__ ffnh,
    const ushort* __restrict__ decT, const ushort* __restrict__ fW2T,
    const float* __restrict__ fb2,
    float* __restrict__ dec_out, float* __restrict__ ffn_out) {
    int z = blockIdx.z;
    const ushort* A = z ? ffnh : gated;
    const ushort* Bt = z ? fW2T : decT;
    const float* bias = z ? fb2 : nullptr;
    float* C = z ? ffn_out : dec_out;
    const int Kd = 1024, N = 256;
    __shared__ __align__(16) ushort As[64 * LDK];
    __shared__ __align__(16) ushort Bs[64 * LDK];
    int tid = threadIdx.x;
    int wid = tid >> 6, lane = tid & 63;
    int brow = blockIdx.y * 64, bcol = blockIdx.x * 64;
    int wr = wid >> 1, wc = wid & 1;     // 2x2 waves, 32x32 each
    f32x4 acc[2][2] = {};
    for (int k0 = 0; k0 < Kd; k0 += 64) {
        __syncthreads();
        #pragma unroll
        for (int j = 0; j < 2; ++j) {
            int idx = tid + j * 256;
            int r = idx >> 3, sgm = idx & 7;
            *(short8v*)&As[r * LDK + sgm * 8] =
                *(const short8v*)&A[(long)(brow + r) * Kd + k0 + sgm * 8];
            *(short8v*)&Bs[r * LDK + sgm * 8] =
                *(const short8v*)&Bt[(long)(bcol + r) * Kd + k0 + sgm * 8];
        }
        __syncthreads();
        #pragma unroll
        for (int kk = 0; kk < 2; ++kk) {
            short8v af[2], bfv[2];
            #pragma unroll
            for (int m = 0; m < 2; ++m)
                af[m] = *(const short8v*)&As[(wr * 32 + m * 16 + (lane & 15)) * LDK + kk * 32 + (lane >> 4) * 8];
            #pragma unroll
            for (int n = 0; n < 2; ++n)
                bfv[n] = *(const short8v*)&Bs[(wc * 32 + n * 16 + (lane & 15)) * LDK + kk * 32 + (lane >> 4) * 8];
            #pragma unroll
            for (int m = 0; m < 2; ++m)
                #pragma unroll
                for (int n = 0; n < 2; ++n)
                    acc[m][n] = __builtin_amdgcn_mfma_f32_16x16x32_bf16(af[m], bfv[n], acc[m][n], 0, 0, 0);
        }
    }
    int r0 = brow + wr * 32 + ((lane >> 4) << 2);
    int c0 = bcol + wc * 32 + (lane & 15);
    #pragma unroll
    for (int n = 0; n < 2; ++n) {
        int col = c0 + n * 16;
        float bv = bias ? bias[col] : 0.0f;
        #pragma unroll
        for (int m = 0; m < 2; ++m)
            #pragma unroll
            for (int j = 0; j < 4; ++j)
                C[(long)(r0 + m * 16 + j) * N + col] = acc[m][n][j] + bv;
    }
}

// ---------------- sig reduction (two stage) ----------------
__global__ void sig_stage1(const float* __restrict__ qs,
                           float* __restrict__ ps, float* __restrict__ ps8) {
    int bn = blockIdx.x * 256 + threadIdx.x;
    int tc = blockIdx.y;
    int b = bn >> 10, n = bn & 1023;
    float s = 0.f, s8 = 0.f;
    int t0 = tc * (T_ / TC_);
    for (int t = t0; t < t0 + T_ / TC_; ++t) {
        float v = qs[((long)(b * T_ + t) << 10) + n];
        s += v;
        if ((t & 7) == 0) s8 += v;
    }
    ps[tc * 2048 + bn] = s;
    ps8[tc * 2048 + bn] = s8;
}

__global__ void sig_stage2(const float* __restrict__ ps, const float* __restrict__ ps8,
                           float* __restrict__ sig) {
    int bn = blockIdx.x * 256 + threadIdx.x;
    float s = 0.f, s8 = 0.f;
    for (int tc = 0; tc < TC_; ++tc) { s += ps[tc * 2048 + bn]; s8 += ps8[tc * 2048 + bn]; }
    sig[bn] = s * (1.0f / T_) + 0.5f * s8 * (1.0f / (T_ / 8));
}

// ---------------- metric MLP: wave-per-output reductions ----------------
// hid[b][j] = gelu(mb1[j] + sig[b][:] . mW1T[j][:])    (1024 waves)
__global__ __launch_bounds__(256) void mlp1_kernel(
    const float* __restrict__ sig, const ushort* __restrict__ mW1T,
    const float* __restrict__ mb1, float* __restrict__ hid) {
    int widx = blockIdx.x * 4 + (threadIdx.x >> 6);
    int b = widx >> 9, j = widx & 511;
    int lane = threadIdx.x & 63;
    const float* sg = sig + b * 1024;
    const ushort* w = mW1T + (long)j * 1024;
    float acc = 0.f;
    #pragma unroll
    for (int c = 0; c < 2; ++c) {
        int n0 = c * 512 + lane * 8;
        short8v wv = *(const short8v*)&w[n0];
        float4 s0 = *(const float4*)&sg[n0];
        float4 s1 = *(const float4*)&sg[n0 + 4];
        acc += bf2f((ushort)wv[0]) * s0.x + bf2f((ushort)wv[1]) * s0.y
             + bf2f((ushort)wv[2]) * s0.z + bf2f((ushort)wv[3]) * s0.w
             + bf2f((ushort)wv[4]) * s1.x + bf2f((ushort)wv[5]) * s1.y
             + bf2f((ushort)wv[6]) * s1.z + bf2f((ushort)wv[7]) * s1.w;
    }
    #pragma unroll
    for (int off = 32; off; off >>= 1) acc += __shfl_xor(acc, off);
    if (lane == 0) hid[b * 512 + j] = geluf(acc + mb1[j]);
}

// metric[b][i] = softplus(base[i] + 0.1*(mb2[i] + hid[b][:] . mW2T[i][:])) + 1e-6  (2048 waves)
__global__ __launch_bounds__(256) void mlp2_kernel(
    const float* __restrict__ hid, const ushort* __restrict__ mW2T,
    const float* __restrict__ mb2, const float* __restrict__ base_metric,
    float* __restrict__ metric) {
    int widx = blockIdx.x * 4 + (threadIdx.x >> 6);
    int b = widx >> 10, i = widx & 1023;
    int lane = threadIdx.x & 63;
    const float* hd = hid + b * 512;
    const ushort* w = mW2T + (long)i * 512;
    int j0 = lane * 8;
    short8v wv = *(const short8v*)&w[j0];
    float4 h0 = *(const float4*)&hd[j0];
    float4 h1 = *(const float4*)&hd[j0 + 4];
    float acc = bf2f((ushort)wv[0]) * h0.x + bf2f((ushort)wv[1]) * h0.y
              + bf2f((ushort)wv[2]) * h0.z + bf2f((ushort)wv[3]) * h0.w
              + bf2f((ushort)wv[4]) * h1.x + bf2f((ushort)wv[5]) * h1.y
              + bf2f((ushort)wv[6]) * h1.z + bf2f((ushort)wv[7]) * h1.w;
    #pragma unroll
    for (int off = 32; off; off >>= 1) acc += __shfl_xor(acc, off);
    if (lane == 0) {
        float v = base_metric[i] + 0.1f * (acc + mb2[i]);
        float sp = fmaxf(v, 0.f) + log1pf(expf(-fabsf(v)));
        metric[b * 1024 + i] = sp + 1e-6f;
    }
}

// ---------------- causal K-window + hebbian + gating (bf16 out) ----------------
__global__ __launch_bounds__(256) void window_kernel(
    const float* __restrict__ qs, const float* __restrict__ vs,
    const float* __restrict__ metric, const float* __restrict__ heb,
    ushort* __restrict__ gated) {
    int bt = blockIdx.x >> 1;
    int h = (blockIdx.x & 1) * 4 + (threadIdx.x >> 6);
    int t = bt & (T_ - 1);
    int b = bt >> 10;
    int lane = threadIdx.x & 63;
    long rowbase = ((long)bt * N_) + h * HD_;
    float q0 = qs[rowbase + lane];
    float q1 = qs[rowbase + lane + 64];
    float m0 = metric[(b * H_ + h) * HD_ + lane];
    float m1 = metric[(b * H_ + h) * HD_ + lane + 64];
    float infl[K_];
    float wsum = 0.f;
    #pragma unroll 4
    for (int k = 0; k < K_; ++k) {
        int src = t - (K_ - 1) + k;
        float qw0 = 0.f, qw1 = 0.f;
        if (src >= 0) {
            long rb = ((long)(b * T_ + src) * N_) + h * HD_;
            qw0 = qs[rb + lane]; qw1 = qs[rb + lane + 64];
        }
        float d0 = q0 - qw0, d1 = q1 - qw1;
        float val = m0 * d0 * d0 + m1 * d1 * d1;
        #pragma unroll
        for (int off = 32; off; off >>= 1) val += __shfl_xor(val, off);
        float w = expf(-sqrtf(val + 1e-8f));
        infl[k] = w;
        wsum += w;
    }
    float inv = 1.0f / (wsum + 1e-8f);
    float c0 = 0.f, c1 = 0.f;
    #pragma unroll 4
    for (int k = 0; k < K_; ++k) {
        int src = t - (K_ - 1) + k;
        if (src < 0) continue;
        long rb = ((long)(b * T_ + src) * N_) + h * HD_;
        float w = infl[k] * inv;
        c0 = fmaf(w, vs[rb + lane], c0);
        c1 = fmaf(w, vs[rb + lane + 64], c1);
    }
    float nv = q0 * q0 + q1 * q1;
    #pragma unroll
    for (int off = 32; off; off >>= 1) nv += __shfl_xor(nv, off);
    float invn = 1.0f / fmaxf(sqrtf(nv), 1e-12f);
    const float* hb = heb + (long)h * HD_ * HD_;
    #pragma unroll 4
    for (int dd = 0; dd < HD_; ++dd) {
        float qd = ((dd < 64) ? __shfl(q0, dd) : __shfl(q1, dd - 64)) * invn;
        c0 = fmaf(qd, hb[dd * HD_ + lane], c0);
        c1 = fmaf(qd, hb[dd * HD_ + lane + 64], c1);
    }
    gated[rowbase + lane] = f2bf(q0 * c0);
    gated[rowbase + lane + 64] = f2bf(q1 * c1);
}

extern "C" void kernel_launch(void* const* d_in, const int* in_sizes, int n_in,
                              void* d_out, int out_size, void* d_ws, size_t ws_size,
                              hipStream_t stream) {
    const int*   tokens      = (const int*)  d_in[0];
    const float* emb         = (const float*)d_in[1];
    const float* field_init  = (const float*)d_in[2];
    const float* Wq          = (const float*)d_in[3];
    const float* Wv          = (const float*)d_in[4];
    const float* mW1         = (const float*)d_in[5];
    const float* mb1         = (const float*)d_in[6];
    const float* mW2         = (const float*)d_in[7];
    const float* mb2         = (const float*)d_in[8];
    const float* base_metric = (const float*)d_in[9];
    const float* decoder     = (const float*)d_in[10];
    const float* hebbian     = (const float*)d_in[11];
    const float* fW1         = (const float*)d_in[12];
    const float* fb1         = (const float*)d_in[13];
    const float* fW2         = (const float*)d_in[14];
    const float* fb2         = (const float*)d_in[15];
    const float* g1          = (const float*)d_in[16];
    const float* b1          = (const float*)d_in[17];
    const float* g2          = (const float*)d_in[18];
    const float* b2          = (const float*)d_in[19];
    const float* gf          = (const float*)d_in[20];
    const float* bf          = (const float*)d_in[21];
    const float* Wl          = (const float*)d_in[22];
    const float* bl          = (const float*)d_in[23];
    float* out = (float*)d_out;

    char* wp = (char*)d_ws;
    auto alloc = [&](size_t bytes) { char* p = wp; wp += (bytes + 255) & ~255UL; return p; };
    float*  x        = (float*) alloc(524288 * 4);
    ushort* y1_bf    = (ushort*)alloc(524288 * 2);
    ushort* y2_bf    = (ushort*)alloc(524288 * 2);
    ushort* yf_bf    = (ushort*)alloc(524288 * 2);
    float*  qs       = (float*) alloc(2097152 * 4);   // } WlT aliases qs+vs (16MB)
    float*  vs       = (float*) alloc(2097152 * 4);   // }
    ushort* gated_bf = (ushort*)alloc(2097152 * 2);
    ushort* ffnh_bf  = (ushort*)alloc(2097152 * 2);
    float*  dec_out  = (float*) alloc(524288 * 4);
    float*  ffn_out  = (float*) alloc(524288 * 4);
    ushort* WqT      = (ushort*)alloc(262144 * 2);
    ushort* WvT      = (ushort*)alloc(262144 * 2);
    ushort* decT     = (ushort*)alloc(262144 * 2);
    ushort* fW1T     = (ushort*)alloc(262144 * 2);
    ushort* fW2T     = (ushort*)alloc(262144 * 2);
    ushort* mW1T     = (ushort*)alloc(524288 * 2);
    ushort* mW2T     = (ushort*)alloc(524288 * 2);
    float*  ps       = (float*) alloc(TC_ * 2048 * 4);
    float*  ps8      = (float*) alloc(TC_ * 2048 * 4);
    float*  sigb     = (float*) alloc(2048 * 4);
    float*  hid      = (float*) alloc(1024 * 4);
    float*  metricb  = (float*) alloc(2048 * 4);
    ushort* WlT      = (ushort*)qs;                   // 32000*256*2 = 16MB over qs+vs

    // weight transpose-casts (f32 [R][C] -> bf16 [C][R])
    tcast_kernel<<<dim3(2, 4, 8), 256, 0, stream>>>(Wq, WqT, 256, 128, 256 * 128, 128 * 256);
    tcast_kernel<<<dim3(2, 4, 8), 256, 0, stream>>>(Wv, WvT, 256, 128, 256 * 128, 128 * 256);
    tcast_kernel<<<dim3(4, 16, 1), 256, 0, stream>>>(decoder, decT, 1024, 256, 0, 0);
    tcast_kernel<<<dim3(16, 4, 1), 256, 0, stream>>>(fW1, fW1T, 256, 1024, 0, 0);
    tcast_kernel<<<dim3(4, 16, 1), 256, 0, stream>>>(fW2, fW2T, 1024, 256, 0, 0);
    tcast_kernel<<<dim3(8, 16, 1), 256, 0, stream>>>(mW1, mW1T, 1024, 512, 0, 0);
    tcast_kernel<<<dim3(16, 8, 1), 256, 0, stream>>>(mW2, mW2T, 512, 1024, 0, 0);

    embed_rope_kernel<<<B_ * T_, 256, 0, stream>>>(tokens, emb, field_init, x);

    for (int step = 0; step < 2; ++step) {
        ln_kernel<<<B_ * T_, 256, 0, stream>>>(
            x, step ? dec_out : nullptr, step ? ffn_out : nullptr,
            g1, b1, g2, b2, y1_bf, y2_bf);
        gemm3_kernel<<<dim3(8, 16, 3), 256, 0, stream>>>(
            y1_bf, y2_bf, WqT, WvT, fW1T, fb1, qs, vs, ffnh_bf);
        sig_stage1<<<dim3(8, TC_), 256, 0, stream>>>(qs, ps, ps8);
        sig_stage2<<<8, 256, 0, stream>>>(ps, ps8, sigb);
        mlp1_kernel<<<256, 256, 0, stream>>>(sigb, mW1T, mb1, hid);
        mlp2_kernel<<<512, 256, 0, stream>>>(hid, mW2T, mb2, base_metric, metricb);
        window_kernel<<<B_ * T_ * 2, 256, 0, stream>>>(qs, vs, metricb, hebbian, gated_bf);
        if (step == 1)  // WlT overwrite of qs/vs is safe after last window
            tcast_kernel<<<dim3(500, 4, 1), 256, 0, stream>>>(Wl, WlT, 256, VOCAB_, 0, 0);
        gemm2_kernel<<<dim3(4, 32, 2), 256, 0, stream>>>(
            gated_bf, ffnh_bf, decT, fW2T, fb2, dec_out, ffn_out);
    }
    // final LN (with fused residual add) + vocab projection
    ln_kernel<<<B_ * T_, 256, 0, stream>>>(x, dec_out, ffn_out, gf, bf, nullptr, nullptr, yf_bf, nullptr);
    vocab_kernel<<<4000, 256, 0, stream>>>(yf_bf, WlT, bl, out);
}

// Round 4
// 431.811 us; speedup vs baseline: 2.8302x; 1.1581x over previous
//
#include <hip/hip_runtime.h>
#include <hip/hip_bf16.h>
#include <math.h>

#define B_ 2
#define T_ 1024
#define D_ 256
#define N_ 1024
#define H_ 8
#define HD_ 128
#define K_ 32
#define VOCAB_ 32000
#define TC_ 16

typedef __attribute__((ext_vector_type(8))) short short8v;
typedef __attribute__((ext_vector_type(4))) float f32x4;

static __device__ __forceinline__ float geluf(float x) {
    return 0.5f * x * (1.0f + erff(x * 0.70710678118654752f));
}

static __device__ __forceinline__ ushort f2bf(float f) {
    unsigned u = __builtin_bit_cast(unsigned, f);
    u += 0x7fff + ((u >> 16) & 1);
    return (ushort)(u >> 16);
}

static __device__ __forceinline__ float bf2f(ushort u) {
    unsigned v = ((unsigned)u) << 16;
    return __builtin_bit_cast(float, v);
}

// ---------------- fused embed + quantized RoPE + dual LayerNorm ----------------
__global__ void embed_rope_ln_kernel(const int* __restrict__ tokens,
                                     const float* __restrict__ emb,
                                     const float* __restrict__ field_init,
                                     const float* __restrict__ g1, const float* __restrict__ b1,
                                     const float* __restrict__ g2, const float* __restrict__ b2,
                                     float* __restrict__ x,
                                     ushort* __restrict__ y1, ushort* __restrict__ y2) {
    int bt = blockIdx.x;
    int d = threadIdx.x;
    int t = bt & (T_ - 1);
    int tok = tokens[bt];
    float v = emb[(long)tok * D_ + d] + field_init[d];
    float partner = __shfl_xor(v, 1);
    float rot = (d & 1) ? partner : -partner;
    float freq = exp2f(-0.0625f * (float)(d & ~1)) * (1.0f / 6.283185307179586f);
    float ph = fmodf((float)t * freq, 1.0f) * 6.283185307179586f;
    v = v * cosf(ph) + rot * sinf(ph);
    long i = (long)bt * D_ + d;
    x[i] = v;
    __shared__ float red[4];
    int lane = d & 63, wid = d >> 6;
    float s = v;
    #pragma unroll
    for (int off = 32; off; off >>= 1) s += __shfl_xor(s, off);
    if (lane == 0) red[wid] = s;
    __syncthreads();
    float mu = (red[0] + red[1] + red[2] + red[3]) * (1.0f / D_);
    float dv = v - mu;
    float s2 = dv * dv;
    #pragma unroll
    for (int off = 32; off; off >>= 1) s2 += __shfl_xor(s2, off);
    __syncthreads();
    if (lane == 0) red[wid] = s2;
    __syncthreads();
    float var = (red[0] + red[1] + red[2] + red[3]) * (1.0f / D_);
    float rstd = rsqrtf(var + 1e-5f);
    float nv = dv * rstd;
    y1[i] = f2bf(nv * g1[d] + b1[d]);
    y2[i] = f2bf(nv * g2[d] + b2[d]);
}

// ---------------- LayerNorm (+ residual add) -> bf16 outputs ----------------
__global__ void ln_kernel(float* __restrict__ x,
                          const float* __restrict__ addA, const float* __restrict__ addB,
                          const float* __restrict__ g1, const float* __restrict__ b1,
                          const float* __restrict__ g2, const float* __restrict__ b2,
                          ushort* __restrict__ y1, ushort* __restrict__ y2) {
    int row = blockIdx.x;
    int d = threadIdx.x;
    long i = (long)row * D_ + d;
    float v = x[i] + addA[i] + addB[i];
    x[i] = v;
    __shared__ float red[4];
    int lane = d & 63, wid = d >> 6;
    float s = v;
    #pragma unroll
    for (int off = 32; off; off >>= 1) s += __shfl_xor(s, off);
    if (lane == 0) red[wid] = s;
    __syncthreads();
    float mu = (red[0] + red[1] + red[2] + red[3]) * (1.0f / D_);
    float dv = v - mu;
    float s2 = dv * dv;
    #pragma unroll
    for (int off = 32; off; off >>= 1) s2 += __shfl_xor(s2, off);
    __syncthreads();
    if (lane == 0) red[wid] = s2;
    __syncthreads();
    float var = (red[0] + red[1] + red[2] + red[3]) * (1.0f / D_);
    float rstd = rsqrtf(var + 1e-5f);
    float nv = dv * rstd;
    y1[i] = f2bf(nv * g1[d] + b1[d]);
    if (y2) y2[i] = f2bf(nv * g2[d] + b2[d]);
}

// ---------------- transpose-cast tile body ----------------
static __device__ __forceinline__ void tcast_tile(
    const float* __restrict__ in, ushort* __restrict__ out,
    int R, int C, int ry, int cx) {
    __shared__ float sm[64][65];
    int r0 = ry * 64, c0 = cx * 64;
    int tx = threadIdx.x & 63, ty = threadIdx.x >> 6;
    #pragma unroll
    for (int i = 0; i < 16; ++i) {
        int r = i * 4 + ty;
        sm[r][tx] = in[(long)(r0 + r) * C + c0 + tx];
    }
    __syncthreads();
    #pragma unroll
    for (int i = 0; i < 16; ++i) {
        int c = i * 4 + ty;
        out[(long)(c0 + c) * R + r0 + tx] = f2bf(sm[tx][c]);
    }
}

// single-weight transpose-cast (used for Wl)
__global__ __launch_bounds__(256) void tcast_kernel(
    const float* __restrict__ in, ushort* __restrict__ out, int R, int C) {
    tcast_tile(in, out, R, C, blockIdx.y, blockIdx.x);
}

// batched transpose-cast: 8 descriptors in one launch
struct TcastBatch {
    const float* in[8];
    ushort* out[8];
    long inS[8], outS[8];
    int cb[8], rb[8], R[8], C[8];
    int cum[9];
};

__global__ __launch_bounds__(256) void tcast_all_kernel(TcastBatch tb) {
    int bid = blockIdx.x;
    int d = 0;
    #pragma unroll
    for (int i = 0; i < 8; ++i) if (bid >= tb.cum[i + 1]) d = i + 1;
    int local = bid - tb.cum[d];
    int bpz = tb.cb[d] * tb.rb[d];
    int z = local / bpz;
    int rem = local - z * bpz;
    int cx = rem % tb.cb[d], ry = rem / tb.cb[d];
    tcast_tile(tb.in[d] + z * tb.inS[d], tb.out[d] + z * tb.outS[d],
               tb.R[d], tb.C[d], ry, cx);
}

// ================= 128x128 MFMA core, BK=64 (LDK=72: 2-way banks, free) =============
#define LDK 72

__device__ __forceinline__ void gemm128_core(
    const ushort* __restrict__ A, int lda,
    const ushort* __restrict__ Bt, int ldb,
    const float* __restrict__ bias, void* __restrict__ Cout, int ldc,
    int Kd, int bx, int by, int act, int outbf) {
    __shared__ __align__(16) ushort As[128 * LDK];
    __shared__ __align__(16) ushort Bs[128 * LDK];
    int tid = threadIdx.x;
    int wid = tid >> 6, lane = tid & 63;
    int brow = by * 128, bcol = bx * 128;
    int wr = wid >> 1, wc = wid & 1;
    f32x4 acc[4][4] = {};
    for (int k0 = 0; k0 < Kd; k0 += 64) {
        __syncthreads();
        #pragma unroll
        for (int j = 0; j < 4; ++j) {
            int idx = tid + j * 256;
            int r = idx >> 3, sgm = idx & 7;
            *(short8v*)&As[r * LDK + sgm * 8] =
                *(const short8v*)&A[(long)(brow + r) * lda + k0 + sgm * 8];
            *(short8v*)&Bs[r * LDK + sgm * 8] =
                *(const short8v*)&Bt[(long)(bcol + r) * ldb + k0 + sgm * 8];
        }
        __syncthreads();
        #pragma unroll
        for (int kk = 0; kk < 2; ++kk) {
            short8v af[4], bfv[4];
            #pragma unroll
            for (int m = 0; m < 4; ++m)
                af[m] = *(const short8v*)&As[(wr * 64 + m * 16 + (lane & 15)) * LDK + kk * 32 + (lane >> 4) * 8];
            #pragma unroll
            for (int n = 0; n < 4; ++n)
                bfv[n] = *(const short8v*)&Bs[(wc * 64 + n * 16 + (lane & 15)) * LDK + kk * 32 + (lane >> 4) * 8];
            #pragma unroll
            for (int m = 0; m < 4; ++m)
                #pragma unroll
                for (int n = 0; n < 4; ++n)
                    acc[m][n] = __builtin_amdgcn_mfma_f32_16x16x32_bf16(af[m], bfv[n], acc[m][n], 0, 0, 0);
        }
    }
    int r0 = brow + wr * 64 + ((lane >> 4) << 2);
    int c0 = bcol + wc * 64 + (lane & 15);
    #pragma unroll
    for (int n = 0; n < 4; ++n) {
        int col = c0 + n * 16;
        float bv = bias ? bias[col] : 0.0f;
        #pragma unroll
        for (int m = 0; m < 4; ++m) {
            #pragma unroll
            for (int j = 0; j < 4; ++j) {
                float v = acc[m][n][j] + bv;
                if (act == 1) v = fmaxf(v, 0.0f);
                else if (act == 2) v = geluf(v);
                long off = (long)(r0 + m * 16 + j) * ldc + col;
                if (outbf) ((ushort*)Cout)[off] = f2bf(v);
                else       ((float*)Cout)[off] = v;
            }
        }
    }
}

// batched qs/vs/ffn1 (all bf16 out)
__global__ __launch_bounds__(256) void gemm3_kernel(
    const ushort* __restrict__ y1, const ushort* __restrict__ y2,
    const ushort* __restrict__ WqT, const ushort* __restrict__ WvT, const ushort* __restrict__ fW1T,
    const float* __restrict__ fb1,
    ushort* __restrict__ qs, ushort* __restrict__ vs, ushort* __restrict__ ffnh) {
    int z = blockIdx.z;
    const ushort* A = (z == 2) ? y2 : y1;
    const ushort* Bt = (z == 0) ? WqT : (z == 1) ? WvT : fW1T;
    const float* bias = (z == 2) ? fb1 : nullptr;
    void* C = (z == 0) ? (void*)qs : (z == 1) ? (void*)vs : (void*)ffnh;
    gemm128_core(A, 256, Bt, 256, bias, C, 1024, 256, blockIdx.x, blockIdx.y, (z == 2) ? 2 : 1, 1);
}

// hebbian batched-per-head GEMM: hebout[bt, h*128+e] = qn[bt,h,:] . hebT[h][e][:]
__global__ __launch_bounds__(256) void heb_gemm_kernel(
    const ushort* __restrict__ qn, const ushort* __restrict__ hebT,
    float* __restrict__ hebout) {
    int h = blockIdx.z;
    gemm128_core(qn + h * HD_, 1024, hebT + (long)h * HD_ * HD_, HD_,
                 nullptr, hebout + h * HD_, 1024, HD_, 0, blockIdx.y, 0, 0);
}

// vocab projection with XCD-chunked block swizzle (grid 4000 = 8*500)
__global__ __launch_bounds__(256) void vocab_kernel(
    const ushort* __restrict__ yf, const ushort* __restrict__ WlT,
    const float* __restrict__ bl, float* __restrict__ out) {
    int g = blockIdx.x;
    int nid = (g & 7) * 500 + (g >> 3);
    gemm128_core(yf, 256, WlT, 256, bl, out, VOCAB_, 256, nid >> 4, nid & 15, 0, 0);
}

// ================= 64x64 MFMA core for N=256 GEMMs (decoder + FFN2) =============
__global__ __launch_bounds__(256) void gemm2_kernel(
    const ushort* __restrict__ gated, const ushort* __restrict__ ffnh,
    const ushort* __restrict__ decT, const ushort* __restrict__ fW2T,
    const float* __restrict__ fb2,
    float* __restrict__ dec_out, float* __restrict__ ffn_out) {
    int z = blockIdx.z;
    const ushort* A = z ? ffnh : gated;
    const ushort* Bt = z ? fW2T : decT;
    const float* bias = z ? fb2 : nullptr;
    float* C = z ? ffn_out : dec_out;
    const int Kd = 1024, N = 256;
    __shared__ __align__(16) ushort As[64 * LDK];
    __shared__ __align__(16) ushort Bs[64 * LDK];
    int tid = threadIdx.x;
    int wid = tid >> 6, lane = tid & 63;
    int brow = blockIdx.y * 64, bcol = blockIdx.x * 64;
    int wr = wid >> 1, wc = wid & 1;
    f32x4 acc[2][2] = {};
    for (int k0 = 0; k0 < Kd; k0 += 64) {
        __syncthreads();
        #pragma unroll
        for (int j = 0; j < 2; ++j) {
            int idx = tid + j * 256;
            int r = idx >> 3, sgm = idx & 7;
            *(short8v*)&As[r * LDK + sgm * 8] =
                *(const short8v*)&A[(long)(brow + r) * Kd + k0 + sgm * 8];
            *(short8v*)&Bs[r * LDK + sgm * 8] =
                *(const short8v*)&Bt[(long)(bcol + r) * Kd + k0 + sgm * 8];
        }
        __syncthreads();
        #pragma unroll
        for (int kk = 0; kk < 2; ++kk) {
            short8v af[2], bfv[2];
            #pragma unroll
            for (int m = 0; m < 2; ++m)
                af[m] = *(const short8v*)&As[(wr * 32 + m * 16 + (lane & 15)) * LDK + kk * 32 + (lane >> 4) * 8];
            #pragma unroll
            for (int n = 0; n < 2; ++n)
                bfv[n] = *(const short8v*)&Bs[(wc * 32 + n * 16 + (lane & 15)) * LDK + kk * 32 + (lane >> 4) * 8];
            #pragma unroll
            for (int m = 0; m < 2; ++m)
                #pragma unroll
                for (int n = 0; n < 2; ++n)
                    acc[m][n] = __builtin_amdgcn_mfma_f32_16x16x32_bf16(af[m], bfv[n], acc[m][n], 0, 0, 0);
        }
    }
    int r0 = brow + wr * 32 + ((lane >> 4) << 2);
    int c0 = bcol + wc * 32 + (lane & 15);
    #pragma unroll
    for (int n = 0; n < 2; ++n) {
        int col = c0 + n * 16;
        float bv = bias ? bias[col] : 0.0f;
        #pragma unroll
        for (int m = 0; m < 2; ++m)
            #pragma unroll
            for (int j = 0; j < 4; ++j)
                C[(long)(r0 + m * 16 + j) * N + col] = acc[m][n][j] + bv;
    }
}

// ---------------- sig reduction (two stage, bf16 input) ----------------
__global__ void sig_stage1(const ushort* __restrict__ qs,
                           float* __restrict__ ps, float* __restrict__ ps8) {
    int bn = blockIdx.x * 256 + threadIdx.x;
    int tc = blockIdx.y;
    int b = bn >> 10, n = bn & 1023;
    float s = 0.f, s8 = 0.f;
    int t0 = tc * (T_ / TC_);
    for (int t = t0; t < t0 + T_ / TC_; ++t) {
        float v = bf2f(qs[((long)(b * T_ + t) << 10) + n]);
        s += v;
        if ((t & 7) == 0) s8 += v;
    }
    ps[tc * 2048 + bn] = s;
    ps8[tc * 2048 + bn] = s8;
}

__global__ void sig_stage2(const float* __restrict__ ps, const float* __restrict__ ps8,
                           float* __restrict__ sig) {
    int bn = blockIdx.x * 256 + threadIdx.x;
    float s = 0.f, s8 = 0.f;
    for (int tc = 0; tc < TC_; ++tc) { s += ps[tc * 2048 + bn]; s8 += ps8[tc * 2048 + bn]; }
    sig[bn] = s * (1.0f / T_) + 0.5f * s8 * (1.0f / (T_ / 8));
}

// ---------------- metric MLP: wave-per-output reductions ----------------
__global__ __launch_bounds__(256) void mlp1_kernel(
    const float* __restrict__ sig, const ushort* __restrict__ mW1T,
    const float* __restrict__ mb1, float* __restrict__ hid) {
    int widx = blockIdx.x * 4 + (threadIdx.x >> 6);
    int b = widx >> 9, j = widx & 511;
    int lane = threadIdx.x & 63;
    const float* sg = sig + b * 1024;
    const ushort* w = mW1T + (long)j * 1024;
    float acc = 0.f;
    #pragma unroll
    for (int c = 0; c < 2; ++c) {
        int n0 = c * 512 + lane * 8;
        short8v wv = *(const short8v*)&w[n0];
        float4 s0 = *(const float4*)&sg[n0];
        float4 s1 = *(const float4*)&sg[n0 + 4];
        acc += bf2f((ushort)wv[0]) * s0.x + bf2f((ushort)wv[1]) * s0.y
             + bf2f((ushort)wv[2]) * s0.z + bf2f((ushort)wv[3]) * s0.w
             + bf2f((ushort)wv[4]) * s1.x + bf2f((ushort)wv[5]) * s1.y
             + bf2f((ushort)wv[6]) * s1.z + bf2f((ushort)wv[7]) * s1.w;
    }
    #pragma unroll
    for (int off = 32; off; off >>= 1) acc += __shfl_xor(acc, off);
    if (lane == 0) hid[b * 512 + j] = geluf(acc + mb1[j]);
}

__global__ __launch_bounds__(256) void mlp2_kernel(
    const float* __restrict__ hid, const ushort* __restrict__ mW2T,
    const float* __restrict__ mb2, const float* __restrict__ base_metric,
    float* __restrict__ metric) {
    int widx = blockIdx.x * 4 + (threadIdx.x >> 6);
    int b = widx >> 10, i = widx & 1023;
    int lane = threadIdx.x & 63;
    const float* hd = hid + b * 512;
    const ushort* w = mW2T + (long)i * 512;
    int j0 = lane * 8;
    short8v wv = *(const short8v*)&w[j0];
    float4 h0 = *(const float4*)&hd[j0];
    float4 h1 = *(const float4*)&hd[j0 + 4];
    float acc = bf2f((ushort)wv[0]) * h0.x + bf2f((ushort)wv[1]) * h0.y
              + bf2f((ushort)wv[2]) * h0.z + bf2f((ushort)wv[3]) * h0.w
              + bf2f((ushort)wv[4]) * h1.x + bf2f((ushort)wv[5]) * h1.y
              + bf2f((ushort)wv[6]) * h1.z + bf2f((ushort)wv[7]) * h1.w;
    #pragma unroll
    for (int off = 32; off; off >>= 1) acc += __shfl_xor(acc, off);
    if (lane == 0) {
        float v = base_metric[i] + 0.1f * (acc + mb2[i]);
        float sp = fmaxf(v, 0.f) + log1pf(expf(-fabsf(v)));
        metric[b * 1024 + i] = sp + 1e-6f;
    }
}

// ---------------- qn = q / max(||q||, 1e-12)  (bf16 in/out) ----------------
__global__ __launch_bounds__(256) void qn_kernel(
    const ushort* __restrict__ qs, ushort* __restrict__ qn) {
    int bt = blockIdx.x >> 1;
    int h = (blockIdx.x & 1) * 4 + (threadIdx.x >> 6);
    int lane = threadIdx.x & 63;
    long rowbase = (long)bt * N_ + h * HD_;
    uint qp = *(const uint*)&qs[rowbase + 2 * lane];
    float q0 = bf2f((ushort)(qp & 0xffff)), q1 = bf2f((ushort)(qp >> 16));
    float nv = q0 * q0 + q1 * q1;
    #pragma unroll
    for (int off = 32; off; off >>= 1) nv += __shfl_xor(nv, off);
    float invn = 1.0f / fmaxf(sqrtf(nv), 1e-12f);
    uint outp = (uint)f2bf(q0 * invn) | ((uint)f2bf(q1 * invn) << 16);
    *(uint*)&qn[rowbase + 2 * lane] = outp;
}

// ---------------- causal K-window + gate (hebbian via hebout) ----------------
__global__ __launch_bounds__(256) void window_kernel(
    const ushort* __restrict__ qs, const ushort* __restrict__ vs,
    const float* __restrict__ metric, const float* __restrict__ hebout,
    ushort* __restrict__ gated) {
    int bt = blockIdx.x >> 1;
    int h = (blockIdx.x & 1) * 4 + (threadIdx.x >> 6);
    int t = bt & (T_ - 1);
    int b = bt >> 10;
    int lane = threadIdx.x & 63;
    long rowbase = (long)bt * N_ + h * HD_;
    uint qp = *(const uint*)&qs[rowbase + 2 * lane];
    float q0 = bf2f((ushort)(qp & 0xffff)), q1 = bf2f((ushort)(qp >> 16));
    float2 mp = *(const float2*)&metric[(b * H_ + h) * HD_ + 2 * lane];
    float infl[K_];
    float wsum = 0.f;
    #pragma unroll
    for (int k = 0; k < K_; ++k) {
        int src = t - (K_ - 1) + k;
        uint qwp = 0;
        if (src >= 0)
            qwp = *(const uint*)&qs[((long)(b * T_ + src) * N_) + h * HD_ + 2 * lane];
        float d0 = q0 - bf2f((ushort)(qwp & 0xffff));
        float d1 = q1 - bf2f((ushort)(qwp >> 16));
        float val = mp.x * d0 * d0 + mp.y * d1 * d1;
        #pragma unroll
        for (int off = 32; off; off >>= 1) val += __shfl_xor(val, off);
        float w = __expf(-sqrtf(val + 1e-8f));
        infl[k] = w;
        wsum += w;                       // padded positions DO contribute (matches ref)
    }
    float inv = 1.0f / (wsum + 1e-8f);
    float2 hb = *(const float2*)&hebout[rowbase + 2 * lane];
    float c0 = hb.x, c1 = hb.y;
    #pragma unroll
    for (int k = 0; k < K_; ++k) {
        int src = t - (K_ - 1) + k;
        if (src < 0) continue;
        uint vp = *(const uint*)&vs[((long)(b * T_ + src) * N_) + h * HD_ + 2 * lane];
        float w = infl[k] * inv;
        c0 = fmaf(w, bf2f((ushort)(vp & 0xffff)), c0);
        c1 = fmaf(w, bf2f((ushort)(vp >> 16)), c1);
    }
    uint outp = (uint)f2bf(q0 * c0) | ((uint)f2bf(q1 * c1) << 16);
    *(uint*)&gated[rowbase + 2 * lane] = outp;
}

extern "C" void kernel_launch(void* const* d_in, const int* in_sizes, int n_in,
                              void* d_out, int out_size, void* d_ws, size_t ws_size,
                              hipStream_t stream) {
    const int*   tokens      = (const int*)  d_in[0];
    const float* emb         = (const float*)d_in[1];
    const float* field_init  = (const float*)d_in[2];
    const float* Wq          = (const float*)d_in[3];
    const float* Wv          = (const float*)d_in[4];
    const float* mW1         = (const float*)d_in[5];
    const float* mb1         = (const float*)d_in[6];
    const float* mW2         = (const float*)d_in[7];
    const float* mb2         = (const float*)d_in[8];
    const float* base_metric = (const float*)d_in[9];
    const float* decoder     = (const float*)d_in[10];
    const float* hebbian     = (const float*)d_in[11];
    const float* fW1         = (const float*)d_in[12];
    const float* fb1         = (const float*)d_in[13];
    const float* fW2         = (const float*)d_in[14];
    const float* fb2         = (const float*)d_in[15];
    const float* g1          = (const float*)d_in[16];
    const float* b1          = (const float*)d_in[17];
    const float* g2          = (const float*)d_in[18];
    const float* b2          = (const float*)d_in[19];
    const float* gf          = (const float*)d_in[20];
    const float* bf          = (const float*)d_in[21];
    const float* Wl          = (const float*)d_in[22];
    const float* bl          = (const float*)d_in[23];
    float* out = (float*)d_out;

    char* wp = (char*)d_ws;
    auto alloc = [&](size_t bytes) { char* p = wp; wp += (bytes + 255) & ~255UL; return p; };
    float*  x        = (float*) alloc(524288 * 4);
    ushort* y1_bf    = (ushort*)alloc(524288 * 2);
    ushort* y2_bf    = (ushort*)alloc(524288 * 2);
    ushort* yf_bf    = (ushort*)alloc(524288 * 2);
    ushort* qs_bf    = (ushort*)alloc(2097152 * 2);  // } WlT (16MB) aliases these
    ushort* vs_bf    = (ushort*)alloc(2097152 * 2);  // } four contiguous 4MB bufs
    ushort* gated_bf = (ushort*)alloc(2097152 * 2);  // }
    ushort* ffnh_bf  = (ushort*)alloc(2097152 * 2);  // }
    float*  dec_out  = (float*) alloc(524288 * 4);
    float*  ffn_out  = (float*) alloc(524288 * 4);
    ushort* qn_bf    = (ushort*)alloc(2097152 * 2);
    float*  hebout   = (float*) alloc(2097152 * 4);
    ushort* WqT      = (ushort*)alloc(262144 * 2);
    ushort* WvT      = (ushort*)alloc(262144 * 2);
    ushort* decT     = (ushort*)alloc(262144 * 2);
    ushort* fW1T     = (ushort*)alloc(262144 * 2);
    ushort* fW2T     = (ushort*)alloc(262144 * 2);
    ushort* mW1T     = (ushort*)alloc(524288 * 2);
    ushort* mW2T     = (ushort*)alloc(524288 * 2);
    ushort* hebT     = (ushort*)alloc(131072 * 2);
    float*  ps       = (float*) alloc(TC_ * 2048 * 4);
    float*  ps8      = (float*) alloc(TC_ * 2048 * 4);
    float*  sigb     = (float*) alloc(2048 * 4);
    float*  hid      = (float*) alloc(1024 * 4);
    float*  metricb  = (float*) alloc(2048 * 4);
    ushort* WlT      = (ushort*)qs_bf;               // 16MB over qs/vs/gated/ffnh

    // one batched launch for all weight transpose-casts
    TcastBatch tb;
    const float* tin[8]  = {Wq, Wv, decoder, fW1, fW2, mW1, mW2, hebbian};
    ushort*      tout[8] = {WqT, WvT, decT, fW1T, fW2T, mW1T, mW2T, hebT};
    long tinS[8]  = {256 * 128, 256 * 128, 0, 0, 0, 0, 0, 128 * 128};
    long toutS[8] = {128 * 256, 128 * 256, 0, 0, 0, 0, 0, 128 * 128};
    int tR[8] = {256, 256, 1024, 256, 1024, 1024, 512, 128};
    int tC[8] = {128, 128, 256, 1024, 256, 512, 1024, 128};
    int cum = 0;
    tb.cum[0] = 0;
    for (int i = 0; i < 8; ++i) {
        tb.in[i] = tin[i]; tb.out[i] = tout[i];
        tb.inS[i] = tinS[i]; tb.outS[i] = toutS[i];
        tb.R[i] = tR[i]; tb.C[i] = tC[i];
        tb.cb[i] = tC[i] / 64; tb.rb[i] = tR[i] / 64;
        int zc = (i == 0 || i == 1 || i == 7) ? 8 : 1;
        cum += tb.cb[i] * tb.rb[i] * zc;
        tb.cum[i + 1] = cum;
    }
    tcast_all_kernel<<<cum, 256, 0, stream>>>(tb);

    embed_rope_ln_kernel<<<B_ * T_, 256, 0, stream>>>(
        tokens, emb, field_init, g1, b1, g2, b2, x, y1_bf, y2_bf);

    for (int step = 0; step < 2; ++step) {
        if (step == 1)
            ln_kernel<<<B_ * T_, 256, 0, stream>>>(
                x, dec_out, ffn_out, g1, b1, g2, b2, y1_bf, y2_bf);
        gemm3_kernel<<<dim3(8, 16, 3), 256, 0, stream>>>(
            y1_bf, y2_bf, WqT, WvT, fW1T, fb1, qs_bf, vs_bf, ffnh_bf);
        qn_kernel<<<B_ * T_ * 2, 256, 0, stream>>>(qs_bf, qn_bf);
        heb_gemm_kernel<<<dim3(1, 16, 8), 256, 0, stream>>>(qn_bf, hebT, hebout);
        sig_stage1<<<dim3(8, TC_), 256, 0, stream>>>(qs_bf, ps, ps8);
        sig_stage2<<<8, 256, 0, stream>>>(ps, ps8, sigb);
        mlp1_kernel<<<256, 256, 0, stream>>>(sigb, mW1T, mb1, hid);
        mlp2_kernel<<<512, 256, 0, stream>>>(hid, mW2T, mb2, base_metric, metricb);
        window_kernel<<<B_ * T_ * 2, 256, 0, stream>>>(
            qs_bf, vs_bf, metricb, hebout, gated_bf);
        gemm2_kernel<<<dim3(4, 32, 2), 256, 0, stream>>>(
            gated_bf, ffnh_bf, decT, fW2T, fb2, dec_out, ffn_out);
    }
    // final LN (fused residual) + vocab projection
    ln_kernel<<<B_ * T_, 256, 0, stream>>>(
        x, dec_out, ffn_out, gf, bf, nullptr, nullptr, yf_bf, nullptr);
    tcast_kernel<<<dim3(500, 4), 256, 0, stream>>>(Wl, WlT, 256, VOCAB_);
    vocab_kernel<<<4000, 256, 0, stream>>>(yf_bf, WlT, bl, out);
}

// Round 5
// 317.804 us; speedup vs baseline: 3.8454x; 1.3587x over previous
//
#include <hip/hip_runtime.h>
#include <hip/hip_bf16.h>
#include <math.h>

#define B_ 2
#define T_ 1024
#define D_ 256
#define N_ 1024
#define H_ 8
#define HD_ 128
#define K_ 32
#define VOCAB_ 32000
#define TC_ 16

typedef __attribute__((ext_vector_type(8))) short short8v;
typedef __attribute__((ext_vector_type(4))) float f32x4;

static __device__ __forceinline__ float geluf(float x) {
    return 0.5f * x * (1.0f + erff(x * 0.70710678118654752f));
}

static __device__ __forceinline__ ushort f2bf(float f) {
    unsigned u = __builtin_bit_cast(unsigned, f);
    u += 0x7fff + ((u >> 16) & 1);
    return (ushort)(u >> 16);
}

static __device__ __forceinline__ float bf2f(ushort u) {
    unsigned v = ((unsigned)u) << 16;
    return __builtin_bit_cast(float, v);
}

// ---------------- fused embed + quantized RoPE + dual LayerNorm ----------------
__global__ void embed_rope_ln_kernel(const int* __restrict__ tokens,
                                     const float* __restrict__ emb,
                                     const float* __restrict__ field_init,
                                     const float* __restrict__ g1, const float* __restrict__ b1,
                                     const float* __restrict__ g2, const float* __restrict__ b2,
                                     float* __restrict__ x,
                                     ushort* __restrict__ y1, ushort* __restrict__ y2) {
    int bt = blockIdx.x;
    int d = threadIdx.x;
    int t = bt & (T_ - 1);
    int tok = tokens[bt];
    float v = emb[(long)tok * D_ + d] + field_init[d];
    float partner = __shfl_xor(v, 1);
    float rot = (d & 1) ? partner : -partner;
    float freq = exp2f(-0.0625f * (float)(d & ~1)) * (1.0f / 6.283185307179586f);
    float ph = fmodf((float)t * freq, 1.0f) * 6.283185307179586f;
    v = v * cosf(ph) + rot * sinf(ph);
    long i = (long)bt * D_ + d;
    x[i] = v;
    __shared__ float red[4];
    int lane = d & 63, wid = d >> 6;
    float s = v;
    #pragma unroll
    for (int off = 32; off; off >>= 1) s += __shfl_xor(s, off);
    if (lane == 0) red[wid] = s;
    __syncthreads();
    float mu = (red[0] + red[1] + red[2] + red[3]) * (1.0f / D_);
    float dv = v - mu;
    float s2 = dv * dv;
    #pragma unroll
    for (int off = 32; off; off >>= 1) s2 += __shfl_xor(s2, off);
    __syncthreads();
    if (lane == 0) red[wid] = s2;
    __syncthreads();
    float var = (red[0] + red[1] + red[2] + red[3]) * (1.0f / D_);
    float rstd = rsqrtf(var + 1e-5f);
    float nv = dv * rstd;
    y1[i] = f2bf(nv * g1[d] + b1[d]);
    y2[i] = f2bf(nv * g2[d] + b2[d]);
}

// ---------------- LayerNorm (+ residual add) -> bf16 outputs ----------------
__global__ void ln_kernel(float* __restrict__ x,
                          const float* __restrict__ addA, const float* __restrict__ addB,
                          const float* __restrict__ g1, const float* __restrict__ b1,
                          const float* __restrict__ g2, const float* __restrict__ b2,
                          ushort* __restrict__ y1, ushort* __restrict__ y2) {
    int row = blockIdx.x;
    int d = threadIdx.x;
    long i = (long)row * D_ + d;
    float v = x[i] + addA[i] + addB[i];
    x[i] = v;
    __shared__ float red[4];
    int lane = d & 63, wid = d >> 6;
    float s = v;
    #pragma unroll
    for (int off = 32; off; off >>= 1) s += __shfl_xor(s, off);
    if (lane == 0) red[wid] = s;
    __syncthreads();
    float mu = (red[0] + red[1] + red[2] + red[3]) * (1.0f / D_);
    float dv = v - mu;
    float s2 = dv * dv;
    #pragma unroll
    for (int off = 32; off; off >>= 1) s2 += __shfl_xor(s2, off);
    __syncthreads();
    if (lane == 0) red[wid] = s2;
    __syncthreads();
    float var = (red[0] + red[1] + red[2] + red[3]) * (1.0f / D_);
    float rstd = rsqrtf(var + 1e-5f);
    float nv = dv * rstd;
    y1[i] = f2bf(nv * g1[d] + b1[d]);
    if (y2) y2[i] = f2bf(nv * g2[d] + b2[d]);
}

// ---------------- transpose-cast tile body ----------------
static __device__ __forceinline__ void tcast_tile(
    const float* __restrict__ in, ushort* __restrict__ out,
    int R, int C, int ry, int cx) {
    __shared__ float sm[64][65];
    int r0 = ry * 64, c0 = cx * 64;
    int tx = threadIdx.x & 63, ty = threadIdx.x >> 6;
    #pragma unroll
    for (int i = 0; i < 16; ++i) {
        int r = i * 4 + ty;
        sm[r][tx] = in[(long)(r0 + r) * C + c0 + tx];
    }
    __syncthreads();
    #pragma unroll
    for (int i = 0; i < 16; ++i) {
        int c = i * 4 + ty;
        out[(long)(c0 + c) * R + r0 + tx] = f2bf(sm[tx][c]);
    }
}

__global__ __launch_bounds__(256) void tcast_kernel(
    const float* __restrict__ in, ushort* __restrict__ out, int R, int C) {
    tcast_tile(in, out, R, C, blockIdx.y, blockIdx.x);
}

struct TcastBatch {
    const float* in[8];
    ushort* out[8];
    long inS[8], outS[8];
    int cb[8], rb[8], R[8], C[8];
    int cum[9];
};

__global__ __launch_bounds__(256) void tcast_all_kernel(TcastBatch tb) {
    int bid = blockIdx.x;
    int d = 0;
    #pragma unroll
    for (int i = 0; i < 8; ++i) if (bid >= tb.cum[i + 1]) d = i + 1;
    int local = bid - tb.cum[d];
    int bpz = tb.cb[d] * tb.rb[d];
    int z = local / bpz;
    int rem = local - z * bpz;
    int cx = rem % tb.cb[d], ry = rem / tb.cb[d];
    tcast_tile(tb.in[d] + z * tb.inS[d], tb.out[d] + z * tb.outS[d],
               tb.R[d], tb.C[d], ry, cx);
}

// ================= 128x128 MFMA core, BK=64; LDS-staged full-line epilogue =============
#define LDK 72
#define CSTR 132   // f32 stride for epilogue staging

__device__ __forceinline__ void gemm128_core(
    const ushort* __restrict__ A, int lda,
    const ushort* __restrict__ Bt, int ldb,
    const float* __restrict__ bias, void* __restrict__ Cout, int ldc,
    int Kd, int bx, int by, int act, int outbf) {
    __shared__ __align__(16) ushort As[128 * LDK];
    __shared__ __align__(16) ushort Bs[128 * LDK];
    int tid = threadIdx.x;
    int wid = tid >> 6, lane = tid & 63;
    int brow = by * 128, bcol = bx * 128;
    int wr = wid >> 1, wc = wid & 1;
    f32x4 acc[4][4] = {};
    for (int k0 = 0; k0 < Kd; k0 += 64) {
        __syncthreads();
        #pragma unroll
        for (int j = 0; j < 4; ++j) {
            int idx = tid + j * 256;
            int r = idx >> 3, sgm = idx & 7;
            *(short8v*)&As[r * LDK + sgm * 8] =
                *(const short8v*)&A[(long)(brow + r) * lda + k0 + sgm * 8];
            *(short8v*)&Bs[r * LDK + sgm * 8] =
                *(const short8v*)&Bt[(long)(bcol + r) * ldb + k0 + sgm * 8];
        }
        __syncthreads();
        #pragma unroll
        for (int kk = 0; kk < 2; ++kk) {
            short8v af[4], bfv[4];
            #pragma unroll
            for (int m = 0; m < 4; ++m)
                af[m] = *(const short8v*)&As[(wr * 64 + m * 16 + (lane & 15)) * LDK + kk * 32 + (lane >> 4) * 8];
            #pragma unroll
            for (int n = 0; n < 4; ++n)
                bfv[n] = *(const short8v*)&Bs[(wc * 64 + n * 16 + (lane & 15)) * LDK + kk * 32 + (lane >> 4) * 8];
            #pragma unroll
            for (int m = 0; m < 4; ++m)
                #pragma unroll
                for (int n = 0; n < 4; ++n)
                    acc[m][n] = __builtin_amdgcn_mfma_f32_16x16x32_bf16(af[m], bfv[n], acc[m][n], 0, 0, 0);
        }
    }
    // epilogue: stage 32-row chunks to LDS, write full 128B-line segments
    float* Cs = (float*)As;   // 32*CSTR*4 = 16.9KB <= 18.4KB
    #pragma unroll
    for (int chunk = 0; chunk < 4; ++chunk) {
        __syncthreads();
        if (wr == (chunk >> 1)) {
            #pragma unroll
            for (int mm = 0; mm < 2; ++mm) {
                int m = (chunk & 1) * 2 + mm;
                int lr0 = mm * 16 + ((lane >> 4) << 2);
                #pragma unroll
                for (int n = 0; n < 4; ++n) {
                    int lcol = wc * 64 + n * 16 + (lane & 15);
                    #pragma unroll
                    for (int j = 0; j < 4; ++j)
                        Cs[(lr0 + j) * CSTR + lcol] = acc[m][n][j];
                }
            }
        }
        __syncthreads();
        int lrow = tid >> 3, f4 = tid & 7;
        long grow = brow + chunk * 32 + lrow;
        if (outbf) {
            #pragma unroll
            for (int u = 0; u < 2; ++u) {
                int c0i = (f4 + u * 8) * 8;      // 8 bf16 per 16B packet
                uint pk[4];
                #pragma unroll
                for (int q = 0; q < 4; ++q) {
                    int cc = c0i + 2 * q;
                    float v0 = Cs[lrow * CSTR + cc]     + (bias ? bias[bcol + cc] : 0.0f);
                    float v1 = Cs[lrow * CSTR + cc + 1] + (bias ? bias[bcol + cc + 1] : 0.0f);
                    if (act == 1) { v0 = fmaxf(v0, 0.0f); v1 = fmaxf(v1, 0.0f); }
                    else if (act == 2) { v0 = geluf(v0); v1 = geluf(v1); }
                    pk[q] = (uint)f2bf(v0) | ((uint)f2bf(v1) << 16);
                }
                *(uint4*)&((ushort*)Cout)[grow * ldc + bcol + c0i] = *(uint4*)pk;
            }
        } else {
            #pragma unroll
            for (int u = 0; u < 4; ++u) {
                int c0i = (f4 + u * 8) * 4;      // 4 f32 per 16B packet
                float vv[4];
                #pragma unroll
                for (int q = 0; q < 4; ++q) {
                    float v = Cs[lrow * CSTR + c0i + q] + (bias ? bias[bcol + c0i + q] : 0.0f);
                    if (act == 1) v = fmaxf(v, 0.0f);
                    else if (act == 2) v = geluf(v);
                    vv[q] = v;
                }
                *(float4*)&((float*)Cout)[grow * ldc + bcol + c0i] = *(float4*)vv;
            }
        }
    }
}

// batched qs/vs/ffn1 (all bf16 out)
__global__ __launch_bounds__(256) void gemm3_kernel(
    const ushort* __restrict__ y1, const ushort* __restrict__ y2,
    const ushort* __restrict__ WqT, const ushort* __restrict__ WvT, const ushort* __restrict__ fW1T,
    const float* __restrict__ fb1,
    ushort* __restrict__ qs, ushort* __restrict__ vs, ushort* __restrict__ ffnh) {
    int z = blockIdx.z;
    const ushort* A = (z == 2) ? y2 : y1;
    const ushort* Bt = (z == 0) ? WqT : (z == 1) ? WvT : fW1T;
    const float* bias = (z == 2) ? fb1 : nullptr;
    void* C = (z == 0) ? (void*)qs : (z == 1) ? (void*)vs : (void*)ffnh;
    gemm128_core(A, 256, Bt, 256, bias, C, 1024, 256, blockIdx.x, blockIdx.y, (z == 2) ? 2 : 1, 1);
}

// hebbian batched-per-head GEMM
__global__ __launch_bounds__(256) void heb_gemm_kernel(
    const ushort* __restrict__ qn, const ushort* __restrict__ hebT,
    float* __restrict__ hebout) {
    int h = blockIdx.z;
    gemm128_core(qn + h * HD_, 1024, hebT + (long)h * HD_ * HD_, HD_,
                 nullptr, hebout + h * HD_, 1024, HD_, 0, blockIdx.y, 0, 0);
}

// vocab projection with XCD-chunked block swizzle (grid 4000 = 8*500)
__global__ __launch_bounds__(256) void vocab_kernel(
    const ushort* __restrict__ yf, const ushort* __restrict__ WlT,
    const float* __restrict__ bl, float* __restrict__ out) {
    int g = blockIdx.x;
    int nid = (g & 7) * 500 + (g >> 3);
    gemm128_core(yf, 256, WlT, 256, bl, out, VOCAB_, 256, nid >> 4, nid & 15, 0, 0);
}

// ================= 64x64 MFMA core for N=256 GEMMs (decoder + FFN2) =============
__global__ __launch_bounds__(256) void gemm2_kernel(
    const ushort* __restrict__ gated, const ushort* __restrict__ ffnh,
    const ushort* __restrict__ decT, const ushort* __restrict__ fW2T,
    const float* __restrict__ fb2,
    float* __restrict__ dec_out, float* __restrict__ ffn_out) {
    int z = blockIdx.z;
    const ushort* A = z ? ffnh : gated;
    const ushort* Bt = z ? fW2T : decT;
    const float* bias = z ? fb2 : nullptr;
    float* C = z ? ffn_out : dec_out;
    const int Kd = 1024, N = 256;
    __shared__ __align__(16) ushort As[64 * LDK];
    __shared__ __align__(16) ushort Bs[64 * LDK];
    int tid = threadIdx.x;
    int wid = tid >> 6, lane = tid & 63;
    int brow = blockIdx.y * 64, bcol = blockIdx.x * 64;
    int wr = wid >> 1, wc = wid & 1;
    f32x4 acc[2][2] = {};
    for (int k0 = 0; k0 < Kd; k0 += 64) {
        __syncthreads();
        #pragma unroll
        for (int j = 0; j < 2; ++j) {
            int idx = tid + j * 256;
            int r = idx >> 3, sgm = idx & 7;
            *(short8v*)&As[r * LDK + sgm * 8] =
                *(const short8v*)&A[(long)(brow + r) * Kd + k0 + sgm * 8];
            *(short8v*)&Bs[r * LDK + sgm * 8] =
                *(const short8v*)&Bt[(long)(bcol + r) * Kd + k0 + sgm * 8];
        }
        __syncthreads();
        #pragma unroll
        for (int kk = 0; kk < 2; ++kk) {
            short8v af[2], bfv[2];
            #pragma unroll
            for (int m = 0; m < 2; ++m)
                af[m] = *(const short8v*)&As[(wr * 32 + m * 16 + (lane & 15)) * LDK + kk * 32 + (lane >> 4) * 8];
            #pragma unroll
            for (int n = 0; n < 2; ++n)
                bfv[n] = *(const short8v*)&Bs[(wc * 32 + n * 16 + (lane & 15)) * LDK + kk * 32 + (lane >> 4) * 8];
            #pragma unroll
            for (int m = 0; m < 2; ++m)
                #pragma unroll
                for (int n = 0; n < 2; ++n)
                    acc[m][n] = __builtin_amdgcn_mfma_f32_16x16x32_bf16(af[m], bfv[n], acc[m][n], 0, 0, 0);
        }
    }
    int r0 = brow + wr * 32 + ((lane >> 4) << 2);
    int c0 = bcol + wc * 32 + (lane & 15);
    #pragma unroll
    for (int n = 0; n < 2; ++n) {
        int col = c0 + n * 16;
        float bv = bias ? bias[col] : 0.0f;
        #pragma unroll
        for (int m = 0; m < 2; ++m)
            #pragma unroll
            for (int j = 0; j < 4; ++j)
                C[(long)(r0 + m * 16 + j) * N + col] = acc[m][n][j] + bv;
    }
}

// ---------------- sig reduction (two stage, bf16 input) ----------------
__global__ void sig_stage1(const ushort* __restrict__ qs,
                           float* __restrict__ ps, float* __restrict__ ps8) {
    int bn = blockIdx.x * 256 + threadIdx.x;
    int tc = blockIdx.y;
    int b = bn >> 10, n = bn & 1023;
    float s = 0.f, s8 = 0.f;
    int t0 = tc * (T_ / TC_);
    for (int t = t0; t < t0 + T_ / TC_; ++t) {
        float v = bf2f(qs[((long)(b * T_ + t) << 10) + n]);
        s += v;
        if ((t & 7) == 0) s8 += v;
    }
    ps[tc * 2048 + bn] = s;
    ps8[tc * 2048 + bn] = s8;
}

__global__ void sig_stage2(const float* __restrict__ ps, const float* __restrict__ ps8,
                           float* __restrict__ sig) {
    int bn = blockIdx.x * 256 + threadIdx.x;
    float s = 0.f, s8 = 0.f;
    for (int tc = 0; tc < TC_; ++tc) { s += ps[tc * 2048 + bn]; s8 += ps8[tc * 2048 + bn]; }
    sig[bn] = s * (1.0f / T_) + 0.5f * s8 * (1.0f / (T_ / 8));
}

// ---------------- metric MLP: wave-per-output reductions ----------------
__global__ __launch_bounds__(256) void mlp1_kernel(
    const float* __restrict__ sig, const ushort* __restrict__ mW1T,
    const float* __restrict__ mb1, float* __restrict__ hid) {
    int widx = blockIdx.x * 4 + (threadIdx.x >> 6);
    int b = widx >> 9, j = widx & 511;
    int lane = threadIdx.x & 63;
    const float* sg = sig + b * 1024;
    const ushort* w = mW1T + (long)j * 1024;
    float acc = 0.f;
    #pragma unroll
    for (int c = 0; c < 2; ++c) {
        int n0 = c * 512 + lane * 8;
        short8v wv = *(const short8v*)&w[n0];
        float4 s0 = *(const float4*)&sg[n0];
        float4 s1 = *(const float4*)&sg[n0 + 4];
        acc += bf2f((ushort)wv[0]) * s0.x + bf2f((ushort)wv[1]) * s0.y
             + bf2f((ushort)wv[2]) * s0.z + bf2f((ushort)wv[3]) * s0.w
             + bf2f((ushort)wv[4]) * s1.x + bf2f((ushort)wv[5]) * s1.y
             + bf2f((ushort)wv[6]) * s1.z + bf2f((ushort)wv[7]) * s1.w;
    }
    #pragma unroll
    for (int off = 32; off; off >>= 1) acc += __shfl_xor(acc, off);
    if (lane == 0) hid[b * 512 + j] = geluf(acc + mb1[j]);
}

__global__ __launch_bounds__(256) void mlp2_kernel(
    const float* __restrict__ hid, const ushort* __restrict__ mW2T,
    const float* __restrict__ mb2, const float* __restrict__ base_metric,
    float* __restrict__ metric) {
    int widx = blockIdx.x * 4 + (threadIdx.x >> 6);
    int b = widx >> 10, i = widx & 1023;
    int lane = threadIdx.x & 63;
    const float* hd = hid + b * 512;
    const ushort* w = mW2T + (long)i * 512;
    int j0 = lane * 8;
    short8v wv = *(const short8v*)&w[j0];
    float4 h0 = *(const float4*)&hd[j0];
    float4 h1 = *(const float4*)&hd[j0 + 4];
    float acc = bf2f((ushort)wv[0]) * h0.x + bf2f((ushort)wv[1]) * h0.y
              + bf2f((ushort)wv[2]) * h0.z + bf2f((ushort)wv[3]) * h0.w
              + bf2f((ushort)wv[4]) * h1.x + bf2f((ushort)wv[5]) * h1.y
              + bf2f((ushort)wv[6]) * h1.z + bf2f((ushort)wv[7]) * h1.w;
    #pragma unroll
    for (int off = 32; off; off >>= 1) acc += __shfl_xor(acc, off);
    if (lane == 0) {
        float v = base_metric[i] + 0.1f * (acc + mb2[i]);
        float sp = fmaxf(v, 0.f) + log1pf(expf(-fabsf(v)));
        metric[b * 1024 + i] = sp + 1e-6f;
    }
}

// ---------------- qn = q / max(||q||, 1e-12)  (bf16 in/out) ----------------
__global__ __launch_bounds__(256) void qn_kernel(
    const ushort* __restrict__ qs, ushort* __restrict__ qn) {
    int bt = blockIdx.x >> 1;
    int h = (blockIdx.x & 1) * 4 + (threadIdx.x >> 6);
    int lane = threadIdx.x & 63;
    long rowbase = (long)bt * N_ + h * HD_;
    uint qp = *(const uint*)&qs[rowbase + 2 * lane];
    float q0 = bf2f((ushort)(qp & 0xffff)), q1 = bf2f((ushort)(qp >> 16));
    float nv = q0 * q0 + q1 * q1;
    #pragma unroll
    for (int off = 32; off; off >>= 1) nv += __shfl_xor(nv, off);
    float invn = 1.0f / fmaxf(sqrtf(nv), 1e-12f);
    uint outp = (uint)f2bf(q0 * invn) | ((uint)f2bf(q1 * invn) << 16);
    *(uint*)&qn[rowbase + 2 * lane] = outp;
}

// ---------------- causal K-window, LDS-tiled, sqrt(m)-folded, k-on-lanes ----------------
#define WLDR 67   // uints per LDS row (odd -> conflict-free b32 across k)

__global__ __launch_bounds__(256) void window_kernel(
    const ushort* __restrict__ qs, const ushort* __restrict__ vs,
    const float* __restrict__ metric, const float* __restrict__ hebout,
    ushort* __restrict__ gated) {
    int tile = blockIdx.x, h = blockIdx.y, b = blockIdx.z;
    int t0 = tile * 32;
    int tid = threadIdx.x;
    __shared__ uint Qw[63 * WLDR];
    __shared__ uint Vw[63 * WLDR];
    __shared__ float smf[HD_];
    if (tid < HD_) smf[tid] = sqrtf(metric[(b * H_ + h) * HD_ + tid]);
    __syncthreads();
    // stage rows t0-31 .. t0+31 (63 rows); q scaled by sqrt(metric)
    for (int i = tid; i < 63 * 64; i += 256) {
        int r = i >> 6, c = i & 63;
        int grow = t0 - 31 + r;
        uint qv = 0, vv = 0;
        if (grow >= 0) {
            long base = ((long)(b * T_ + grow) * N_ + h * HD_) >> 1;
            qv = ((const uint*)qs)[base + c];
            vv = ((const uint*)vs)[base + c];
        }
        float q0 = bf2f((ushort)(qv & 0xffff)) * smf[2 * c];
        float q1 = bf2f((ushort)(qv >> 16)) * smf[2 * c + 1];
        Qw[r * WLDR + c] = (uint)f2bf(q0) | ((uint)f2bf(q1) << 16);
        Vw[r * WLDR + c] = vv;
    }
    __syncthreads();
    int w = tid >> 6, lane = tid & 63;
    int k = lane & 31, half = lane >> 5;
    #pragma unroll 2
    for (int i = 0; i < 8; ++i) {
        int lt = w * 8 + i;
        int t = t0 + lt;
        // QK: each lane computes dist partial for its k over its e-half
        const uint* qtrow = &Qw[(lt + 31) * WLDR + half * 32];
        const uint* qsrow = &Qw[(lt + k) * WLDR + half * 32];
        float val = 0.f;
        #pragma unroll
        for (int j = 0; j < 32; ++j) {
            uint a = qtrow[j], s = qsrow[j];
            float d0 = bf2f((ushort)(a & 0xffff)) - bf2f((ushort)(s & 0xffff));
            float d1 = bf2f((ushort)(a >> 16)) - bf2f((ushort)(s >> 16));
            val = fmaf(d0, d0, val);
            val = fmaf(d1, d1, val);
        }
        val += __shfl_xor(val, 32);
        float infl = __expf(-sqrtf(val + 1e-8f));
        float ws = infl;
        #pragma unroll
        for (int off = 16; off; off >>= 1) ws += __shfl_xor(ws, off);
        float wk = infl / (ws + 1e-8f);
        // PV: lane owns uint column `lane` (elems 2*lane, 2*lane+1)
        float c0 = 0.f, c1 = 0.f;
        #pragma unroll
        for (int kk = 0; kk < 32; ++kk) {
            float wkk = __shfl(wk, kk);
            uint vu = Vw[(lt + kk) * WLDR + lane];
            c0 = fmaf(wkk, bf2f((ushort)(vu & 0xffff)), c0);
            c1 = fmaf(wkk, bf2f((ushort)(vu >> 16)), c1);
        }
        // hebbian add + gate with original q
        long rowb = (long)(b * T_ + t) * N_ + h * HD_;
        float2 hb = *(const float2*)&hebout[rowb + 2 * lane];
        uint qo = *(const uint*)&qs[rowb + 2 * lane];
        c0 += hb.x; c1 += hb.y;
        float g0 = bf2f((ushort)(qo & 0xffff)) * c0;
        float g1 = bf2f((ushort)(qo >> 16)) * c1;
        *(uint*)&gated[rowb + 2 * lane] = (uint)f2bf(g0) | ((uint)f2bf(g1) << 16);
    }
}

extern "C" void kernel_launch(void* const* d_in, const int* in_sizes, int n_in,
                              void* d_out, int out_size, void* d_ws, size_t ws_size,
                              hipStream_t stream) {
    const int*   tokens      = (const int*)  d_in[0];
    const float* emb         = (const float*)d_in[1];
    const float* field_init  = (const float*)d_in[2];
    const float* Wq          = (const float*)d_in[3];
    const float* Wv          = (const float*)d_in[4];
    const float* mW1         = (const float*)d_in[5];
    const float* mb1         = (const float*)d_in[6];
    const float* mW2         = (const float*)d_in[7];
    const float* mb2         = (const float*)d_in[8];
    const float* base_metric = (const float*)d_in[9];
    const float* decoder     = (const float*)d_in[10];
    const float* hebbian     = (const float*)d_in[11];
    const float* fW1         = (const float*)d_in[12];
    const float* fb1         = (const float*)d_in[13];
    const float* fW2         = (const float*)d_in[14];
    const float* fb2         = (const float*)d_in[15];
    const float* g1          = (const float*)d_in[16];
    const float* b1          = (const float*)d_in[17];
    const float* g2          = (const float*)d_in[18];
    const float* b2          = (const float*)d_in[19];
    const float* gf          = (const float*)d_in[20];
    const float* bf          = (const float*)d_in[21];
    const float* Wl          = (const float*)d_in[22];
    const float* bl          = (const float*)d_in[23];
    float* out = (float*)d_out;

    char* wp = (char*)d_ws;
    auto alloc = [&](size_t bytes) { char* p = wp; wp += (bytes + 255) & ~255UL; return p; };
    float*  x        = (float*) alloc(524288 * 4);
    ushort* y1_bf    = (ushort*)alloc(524288 * 2);
    ushort* y2_bf    = (ushort*)alloc(524288 * 2);
    ushort* yf_bf    = (ushort*)alloc(524288 * 2);
    ushort* qs_bf    = (ushort*)alloc(2097152 * 2);  // } WlT (16MB) aliases these
    ushort* vs_bf    = (ushort*)alloc(2097152 * 2);  // } four contiguous 4MB bufs
    ushort* gated_bf = (ushort*)alloc(2097152 * 2);  // }
    ushort* ffnh_bf  = (ushort*)alloc(2097152 * 2);  // }
    float*  dec_out  = (float*) alloc(524288 * 4);
    float*  ffn_out  = (float*) alloc(524288 * 4);
    ushort* qn_bf    = (ushort*)alloc(2097152 * 2);
    float*  hebout   = (float*) alloc(2097152 * 4);
    ushort* WqT      = (ushort*)alloc(262144 * 2);
    ushort* WvT      = (ushort*)alloc(262144 * 2);
    ushort* decT     = (ushort*)alloc(262144 * 2);
    ushort* fW1T     = (ushort*)alloc(262144 * 2);
    ushort* fW2T     = (ushort*)alloc(262144 * 2);
    ushort* mW1T     = (ushort*)alloc(524288 * 2);
    ushort* mW2T     = (ushort*)alloc(524288 * 2);
    ushort* hebT     = (ushort*)alloc(131072 * 2);
    float*  ps       = (float*) alloc(TC_ * 2048 * 4);
    float*  ps8      = (float*) alloc(TC_ * 2048 * 4);
    float*  sigb     = (float*) alloc(2048 * 4);
    float*  hid      = (float*) alloc(1024 * 4);
    float*  metricb  = (float*) alloc(2048 * 4);
    ushort* WlT      = (ushort*)qs_bf;               // 16MB over qs/vs/gated/ffnh

    TcastBatch tb;
    const float* tin[8]  = {Wq, Wv, decoder, fW1, fW2, mW1, mW2, hebbian};
    ushort*      tout[8] = {WqT, WvT, decT, fW1T, fW2T, mW1T, mW2T, hebT};
    long tinS[8]  = {256 * 128, 256 * 128, 0, 0, 0, 0, 0, 128 * 128};
    long toutS[8] = {128 * 256, 128 * 256, 0, 0, 0, 0, 0, 128 * 128};
    int tR[8] = {256, 256, 1024, 256, 1024, 1024, 512, 128};
    int tC[8] = {128, 128, 256, 1024, 256, 512, 1024, 128};
    int cum = 0;
    tb.cum[0] = 0;
    for (int i = 0; i < 8; ++i) {
        tb.in[i] = tin[i]; tb.out[i] = tout[i];
        tb.inS[i] = tinS[i]; tb.outS[i] = toutS[i];
        tb.R[i] = tR[i]; tb.C[i] = tC[i];
        tb.cb[i] = tC[i] / 64; tb.rb[i] = tR[i] / 64;
        int zc = (i == 0 || i == 1 || i == 7) ? 8 : 1;
        cum += tb.cb[i] * tb.rb[i] * zc;
        tb.cum[i + 1] = cum;
    }
    tcast_all_kernel<<<cum, 256, 0, stream>>>(tb);

    embed_rope_ln_kernel<<<B_ * T_, 256, 0, stream>>>(
        tokens, emb, field_init, g1, b1, g2, b2, x, y1_bf, y2_bf);

    for (int step = 0; step < 2; ++step) {
        if (step == 1)
            ln_kernel<<<B_ * T_, 256, 0, stream>>>(
                x, dec_out, ffn_out, g1, b1, g2, b2, y1_bf, y2_bf);
        gemm3_kernel<<<dim3(8, 16, 3), 256, 0, stream>>>(
            y1_bf, y2_bf, WqT, WvT, fW1T, fb1, qs_bf, vs_bf, ffnh_bf);
        qn_kernel<<<B_ * T_ * 2, 256, 0, stream>>>(qs_bf, qn_bf);
        heb_gemm_kernel<<<dim3(1, 16, 8), 256, 0, stream>>>(qn_bf, hebT, hebout);
        sig_stage1<<<dim3(8, TC_), 256, 0, stream>>>(qs_bf, ps, ps8);
        sig_stage2<<<8, 256, 0, stream>>>(ps, ps8, sigb);
        mlp1_kernel<<<256, 256, 0, stream>>>(sigb, mW1T, mb1, hid);
        mlp2_kernel<<<512, 256, 0, stream>>>(hid, mW2T, mb2, base_metric, metricb);
        window_kernel<<<dim3(T_ / 32, H_, B_), 256, 0, stream>>>(
            qs_bf, vs_bf, metricb, hebout, gated_bf);
        gemm2_kernel<<<dim3(4, 32, 2), 256, 0, stream>>>(
            gated_bf, ffnh_bf, decT, fW2T, fb2, dec_out, ffn_out);
    }
    ln_kernel<<<B_ * T_, 256, 0, stream>>>(
        x, dec_out, ffn_out, gf, bf, nullptr, nullptr, yf_bf, nullptr);
    tcast_kernel<<<dim3(500, 4), 256, 0, stream>>>(Wl, WlT, 256, VOCAB_);
    vocab_kernel<<<4000, 256, 0, stream>>>(yf_bf, WlT, bl, out);
}

// Round 6
// 312.872 us; speedup vs baseline: 3.9060x; 1.0158x over previous
//
#include <hip/hip_runtime.h>
#include <hip/hip_bf16.h>
#include <math.h>

#define B_ 2
#define T_ 1024
#define D_ 256
#define N_ 1024
#define H_ 8
#define HD_ 128
#define K_ 32
#define VOCAB_ 32000

typedef __attribute__((ext_vector_type(8))) short short8v;
typedef __attribute__((ext_vector_type(4))) float f32x4;

static __device__ __forceinline__ float geluf(float x) {
    return 0.5f * x * (1.0f + erff(x * 0.70710678118654752f));
}

static __device__ __forceinline__ ushort f2bf(float f) {
    unsigned u = __builtin_bit_cast(unsigned, f);
    u += 0x7fff + ((u >> 16) & 1);
    return (ushort)(u >> 16);
}

static __device__ __forceinline__ float bf2f(ushort u) {
    unsigned v = ((unsigned)u) << 16;
    return __builtin_bit_cast(float, v);
}

// ---------------- fused embed + quantized RoPE + dual LayerNorm ----------------
__global__ void embed_rope_ln_kernel(const int* __restrict__ tokens,
                                     const float* __restrict__ emb,
                                     const float* __restrict__ field_init,
                                     const float* __restrict__ g1, const float* __restrict__ b1,
                                     const float* __restrict__ g2, const float* __restrict__ b2,
                                     float* __restrict__ x,
                                     ushort* __restrict__ y1, ushort* __restrict__ y2) {
    int bt = blockIdx.x;
    int d = threadIdx.x;
    int t = bt & (T_ - 1);
    int tok = tokens[bt];
    float v = emb[(long)tok * D_ + d] + field_init[d];
    float partner = __shfl_xor(v, 1);
    float rot = (d & 1) ? partner : -partner;
    float freq = exp2f(-0.0625f * (float)(d & ~1)) * (1.0f / 6.283185307179586f);
    float ph = fmodf((float)t * freq, 1.0f) * 6.283185307179586f;
    v = v * cosf(ph) + rot * sinf(ph);
    long i = (long)bt * D_ + d;
    x[i] = v;
    __shared__ float red[4];
    int lane = d & 63, wid = d >> 6;
    float s = v;
    #pragma unroll
    for (int off = 32; off; off >>= 1) s += __shfl_xor(s, off);
    if (lane == 0) red[wid] = s;
    __syncthreads();
    float mu = (red[0] + red[1] + red[2] + red[3]) * (1.0f / D_);
    float dv = v - mu;
    float s2 = dv * dv;
    #pragma unroll
    for (int off = 32; off; off >>= 1) s2 += __shfl_xor(s2, off);
    __syncthreads();
    if (lane == 0) red[wid] = s2;
    __syncthreads();
    float var = (red[0] + red[1] + red[2] + red[3]) * (1.0f / D_);
    float rstd = rsqrtf(var + 1e-5f);
    float nv = dv * rstd;
    y1[i] = f2bf(nv * g1[d] + b1[d]);
    y2[i] = f2bf(nv * g2[d] + b2[d]);
}

// ---------------- LayerNorm (+ residual add) -> bf16 outputs ----------------
__global__ void ln_kernel(float* __restrict__ x,
                          const float* __restrict__ addA, const float* __restrict__ addB,
                          const float* __restrict__ g1, const float* __restrict__ b1,
                          const float* __restrict__ g2, const float* __restrict__ b2,
                          ushort* __restrict__ y1, ushort* __restrict__ y2) {
    int row = blockIdx.x;
    int d = threadIdx.x;
    long i = (long)row * D_ + d;
    float v = x[i] + addA[i] + addB[i];
    x[i] = v;
    __shared__ float red[4];
    int lane = d & 63, wid = d >> 6;
    float s = v;
    #pragma unroll
    for (int off = 32; off; off >>= 1) s += __shfl_xor(s, off);
    if (lane == 0) red[wid] = s;
    __syncthreads();
    float mu = (red[0] + red[1] + red[2] + red[3]) * (1.0f / D_);
    float dv = v - mu;
    float s2 = dv * dv;
    #pragma unroll
    for (int off = 32; off; off >>= 1) s2 += __shfl_xor(s2, off);
    __syncthreads();
    if (lane == 0) red[wid] = s2;
    __syncthreads();
    float var = (red[0] + red[1] + red[2] + red[3]) * (1.0f / D_);
    float rstd = rsqrtf(var + 1e-5f);
    float nv = dv * rstd;
    y1[i] = f2bf(nv * g1[d] + b1[d]);
    if (y2) y2[i] = f2bf(nv * g2[d] + b2[d]);
}

// ---------------- transpose-cast tile body ----------------
static __device__ __forceinline__ void tcast_tile(
    const float* __restrict__ in, ushort* __restrict__ out,
    int R, int C, int ry, int cx) {
    __shared__ float sm[64][65];
    int r0 = ry * 64, c0 = cx * 64;
    int tx = threadIdx.x & 63, ty = threadIdx.x >> 6;
    #pragma unroll
    for (int i = 0; i < 16; ++i) {
        int r = i * 4 + ty;
        sm[r][tx] = in[(long)(r0 + r) * C + c0 + tx];
    }
    __syncthreads();
    #pragma unroll
    for (int i = 0; i < 16; ++i) {
        int c = i * 4 + ty;
        out[(long)(c0 + c) * R + r0 + tx] = f2bf(sm[tx][c]);
    }
}

__global__ __launch_bounds__(256) void tcast_kernel(
    const float* __restrict__ in, ushort* __restrict__ out, int R, int C) {
    tcast_tile(in, out, R, C, blockIdx.y, blockIdx.x);
}

struct TcastBatch {
    const float* in[8];
    ushort* out[8];
    long inS[8], outS[8];
    int cb[8], rb[8], R[8], C[8];
    int cum[9];
};

__global__ __launch_bounds__(256) void tcast_all_kernel(TcastBatch tb) {
    int bid = blockIdx.x;
    int d = 0;
    #pragma unroll
    for (int i = 0; i < 8; ++i) if (bid >= tb.cum[i + 1]) d = i + 1;
    int local = bid - tb.cum[d];
    int bpz = tb.cb[d] * tb.rb[d];
    int z = local / bpz;
    int rem = local - z * bpz;
    int cx = rem % tb.cb[d], ry = rem / tb.cb[d];
    tcast_tile(tb.in[d] + z * tb.inS[d], tb.out[d] + z * tb.outS[d],
               tb.R[d], tb.C[d], ry, cx);
}

// ================= 128x128 MFMA core, BK=64; LDS-staged epilogue; optional sig =====
#define LDK 72
#define CSTR 132

template<int ACT, int OUTBF, int SIG>
__device__ __forceinline__ void gemm128_core(
    const ushort* __restrict__ A, int lda,
    const ushort* __restrict__ Bt, int ldb,
    const float* __restrict__ bias, void* __restrict__ Cout, int ldc,
    int Kd, int bx, int by,
    float* __restrict__ psOut, float* __restrict__ ps8Out) {
    __shared__ __align__(16) ushort As[128 * LDK];
    __shared__ __align__(16) ushort Bs[128 * LDK];
    int tid = threadIdx.x;
    int wid = tid >> 6, lane = tid & 63;
    int brow = by * 128, bcol = bx * 128;
    int wr = wid >> 1, wc = wid & 1;
    f32x4 acc[4][4] = {};
    for (int k0 = 0; k0 < Kd; k0 += 64) {
        __syncthreads();
        #pragma unroll
        for (int j = 0; j < 4; ++j) {
            int idx = tid + j * 256;
            int r = idx >> 3, sgm = idx & 7;
            *(short8v*)&As[r * LDK + sgm * 8] =
                *(const short8v*)&A[(long)(brow + r) * lda + k0 + sgm * 8];
            *(short8v*)&Bs[r * LDK + sgm * 8] =
                *(const short8v*)&Bt[(long)(bcol + r) * ldb + k0 + sgm * 8];
        }
        __syncthreads();
        #pragma unroll
        for (int kk = 0; kk < 2; ++kk) {
            short8v af[4], bfv[4];
            #pragma unroll
            for (int m = 0; m < 4; ++m)
                af[m] = *(const short8v*)&As[(wr * 64 + m * 16 + (lane & 15)) * LDK + kk * 32 + (lane >> 4) * 8];
            #pragma unroll
            for (int n = 0; n < 4; ++n)
                bfv[n] = *(const short8v*)&Bs[(wc * 64 + n * 16 + (lane & 15)) * LDK + kk * 32 + (lane >> 4) * 8];
            #pragma unroll
            for (int m = 0; m < 4; ++m)
                #pragma unroll
                for (int n = 0; n < 4; ++n)
                    acc[m][n] = __builtin_amdgcn_mfma_f32_16x16x32_bf16(af[m], bfv[n], acc[m][n], 0, 0, 0);
        }
    }
    float* Cs = (float*)As;
    float cs = 0.f, cs8 = 0.f;
    #pragma unroll
    for (int chunk = 0; chunk < 4; ++chunk) {
        __syncthreads();
        if (wr == (chunk >> 1)) {
            #pragma unroll
            for (int mm = 0; mm < 2; ++mm) {
                int m = (chunk & 1) * 2 + mm;
                int lr0 = mm * 16 + ((lane >> 4) << 2);
                #pragma unroll
                for (int n = 0; n < 4; ++n) {
                    int lcol = wc * 64 + n * 16 + (lane & 15);
                    #pragma unroll
                    for (int j = 0; j < 4; ++j)
                        Cs[(lr0 + j) * CSTR + lcol] = acc[m][n][j];
                }
            }
        }
        __syncthreads();
        int lrow = tid >> 3, f4 = tid & 7;
        long grow = brow + chunk * 32 + lrow;
        if (OUTBF) {
            #pragma unroll
            for (int u = 0; u < 2; ++u) {
                int c0i = (f4 + u * 8) * 8;
                uint pk[4];
                #pragma unroll
                for (int q = 0; q < 4; ++q) {
                    int cc = c0i + 2 * q;
                    float v0 = Cs[lrow * CSTR + cc]     + (bias ? bias[bcol + cc] : 0.0f);
                    float v1 = Cs[lrow * CSTR + cc + 1] + (bias ? bias[bcol + cc + 1] : 0.0f);
                    if (ACT == 1) { v0 = fmaxf(v0, 0.0f); v1 = fmaxf(v1, 0.0f); }
                    else if (ACT == 2) { v0 = geluf(v0); v1 = geluf(v1); }
                    pk[q] = (uint)f2bf(v0) | ((uint)f2bf(v1) << 16);
                }
                *(uint4*)&((ushort*)Cout)[grow * ldc + bcol + c0i] = *(uint4*)pk;
            }
        } else {
            #pragma unroll
            for (int u = 0; u < 4; ++u) {
                int c0i = (f4 + u * 8) * 4;
                float vv[4];
                #pragma unroll
                for (int q = 0; q < 4; ++q) {
                    float v = Cs[lrow * CSTR + c0i + q] + (bias ? bias[bcol + c0i + q] : 0.0f);
                    if (ACT == 1) v = fmaxf(v, 0.0f);
                    else if (ACT == 2) v = geluf(v);
                    vv[q] = v;
                }
                *(float4*)&((float*)Cout)[grow * ldc + bcol + c0i] = *(float4*)vv;
            }
        }
        if (SIG && tid < 128) {
            #pragma unroll
            for (int r = 0; r < 32; ++r) {
                float vr = fmaxf(Cs[r * CSTR + tid], 0.0f);
                cs += vr;
                if ((r & 7) == 0) cs8 += vr;
            }
        }
    }
    if (SIG && tid < 128) {
        psOut[by * 1024 + bcol + tid] = cs;
        ps8Out[by * 1024 + bcol + tid] = cs8;
    }
}

// batched qs/vs/ffn1 (bf16 out); z=0 also emits sig partial sums
__global__ __launch_bounds__(256) void gemm3_kernel(
    const ushort* __restrict__ y1, const ushort* __restrict__ y2,
    const ushort* __restrict__ WqT, const ushort* __restrict__ WvT, const ushort* __restrict__ fW1T,
    const float* __restrict__ fb1,
    ushort* __restrict__ qs, ushort* __restrict__ vs, ushort* __restrict__ ffnh,
    float* __restrict__ ps, float* __restrict__ ps8) {
    int z = blockIdx.z;
    if (z == 0)
        gemm128_core<1, 1, 1>(y1, 256, WqT, 256, nullptr, qs, 1024, 256,
                              blockIdx.x, blockIdx.y, ps, ps8);
    else if (z == 1)
        gemm128_core<1, 1, 0>(y1, 256, WvT, 256, nullptr, vs, 1024, 256,
                              blockIdx.x, blockIdx.y, nullptr, nullptr);
    else
        gemm128_core<2, 1, 0>(y2, 256, fW1T, 256, fb1, ffnh, 1024, 256,
                              blockIdx.x, blockIdx.y, nullptr, nullptr);
}

// vocab projection with XCD-chunked block swizzle (grid 4000 = 8*500)
__global__ __launch_bounds__(256) void vocab_kernel(
    const ushort* __restrict__ yf, const ushort* __restrict__ WlT,
    const float* __restrict__ bl, float* __restrict__ out) {
    int g = blockIdx.x;
    int nid = (g & 7) * 500 + (g >> 3);
    gemm128_core<0, 0, 0>(yf, 256, WlT, 256, bl, out, VOCAB_, 256,
                          nid >> 4, nid & 15, nullptr, nullptr);
}

// ================= 64x64 MFMA core for N=256 GEMMs (decoder + FFN2) =============
__global__ __launch_bounds__(256) void gemm2_kernel(
    const ushort* __restrict__ gated, const ushort* __restrict__ ffnh,
    const ushort* __restrict__ decT, const ushort* __restrict__ fW2T,
    const float* __restrict__ fb2,
    float* __restrict__ dec_out, float* __restrict__ ffn_out) {
    int z = blockIdx.z;
    const ushort* A = z ? ffnh : gated;
    const ushort* Bt = z ? fW2T : decT;
    const float* bias = z ? fb2 : nullptr;
    float* C = z ? ffn_out : dec_out;
    const int Kd = 1024, N = 256;
    __shared__ __align__(16) ushort As[64 * LDK];
    __shared__ __align__(16) ushort Bs[64 * LDK];
    int tid = threadIdx.x;
    int wid = tid >> 6, lane = tid & 63;
    int brow = blockIdx.y * 64, bcol = blockIdx.x * 64;
    int wr = wid >> 1, wc = wid & 1;
    f32x4 acc[2][2] = {};
    for (int k0 = 0; k0 < Kd; k0 += 64) {
        __syncthreads();
        #pragma unroll
        for (int j = 0; j < 2; ++j) {
            int idx = tid + j * 256;
            int r = idx >> 3, sgm = idx & 7;
            *(short8v*)&As[r * LDK + sgm * 8] =
                *(const short8v*)&A[(long)(brow + r) * Kd + k0 + sgm * 8];
            *(short8v*)&Bs[r * LDK + sgm * 8] =
                *(const short8v*)&Bt[(long)(bcol + r) * Kd + k0 + sgm * 8];
        }
        __syncthreads();
        #pragma unroll
        for (int kk = 0; kk < 2; ++kk) {
            short8v af[2], bfv[2];
            #pragma unroll
            for (int m = 0; m < 2; ++m)
                af[m] = *(const short8v*)&As[(wr * 32 + m * 16 + (lane & 15)) * LDK + kk * 32 + (lane >> 4) * 8];
            #pragma unroll
            for (int n = 0; n < 2; ++n)
                bfv[n] = *(const short8v*)&Bs[(wc * 32 + n * 16 + (lane & 15)) * LDK + kk * 32 + (lane >> 4) * 8];
            #pragma unroll
            for (int m = 0; m < 2; ++m)
                #pragma unroll
                for (int n = 0; n < 2; ++n)
                    acc[m][n] = __builtin_amdgcn_mfma_f32_16x16x32_bf16(af[m], bfv[n], acc[m][n], 0, 0, 0);
        }
    }
    int r0 = brow + wr * 32 + ((lane >> 4) << 2);
    int c0 = bcol + wc * 32 + (lane & 15);
    #pragma unroll
    for (int n = 0; n < 2; ++n) {
        int col = c0 + n * 16;
        float bv = bias ? bias[col] : 0.0f;
        #pragma unroll
        for (int m = 0; m < 2; ++m)
            #pragma unroll
            for (int j = 0; j < 4; ++j)
                C[(long)(r0 + m * 16 + j) * N + col] = acc[m][n][j] + bv;
    }
}

// ---------------- metric MLP stage 1 (fused ps reduction) ----------------
__global__ __launch_bounds__(256) void mlp1_kernel(
    const float* __restrict__ ps, const float* __restrict__ ps8,
    const ushort* __restrict__ mW1T, const float* __restrict__ mb1,
    float* __restrict__ hid) {
    int blk = blockIdx.x;              // 256 blocks; 128 per b
    int b = blk >> 7;
    __shared__ float sig_l[1024];
    int tid = threadIdx.x;
    for (int c = tid; c < 1024; c += 256) {
        float s = 0.f, s8 = 0.f;
        #pragma unroll
        for (int by8 = 0; by8 < 8; ++by8) {
            s += ps[(b * 8 + by8) * 1024 + c];
            s8 += ps8[(b * 8 + by8) * 1024 + c];
        }
        sig_l[c] = s * (1.0f / 1024.0f) + 0.5f * s8 * (1.0f / 128.0f);
    }
    __syncthreads();
    int wv = tid >> 6, lane = tid & 63;
    int j = (blk & 127) * 4 + wv;      // 0..511
    const ushort* wrow = mW1T + (long)j * 1024;
    float acc = 0.f;
    #pragma unroll
    for (int c2 = 0; c2 < 4; ++c2) {
        int n0 = c2 * 256 + lane * 4;
        float4 sv = *(const float4*)&sig_l[n0];
        ushort4 w4 = *(const ushort4*)&wrow[n0];
        acc += bf2f(w4.x) * sv.x + bf2f(w4.y) * sv.y
             + bf2f(w4.z) * sv.z + bf2f(w4.w) * sv.w;
    }
    #pragma unroll
    for (int off = 32; off; off >>= 1) acc += __shfl_xor(acc, off);
    if (lane == 0) hid[b * 512 + j] = geluf(acc + mb1[j]);
}

__global__ __launch_bounds__(256) void mlp2_kernel(
    const float* __restrict__ hid, const ushort* __restrict__ mW2T,
    const float* __restrict__ mb2, const float* __restrict__ base_metric,
    float* __restrict__ metric) {
    int widx = blockIdx.x * 4 + (threadIdx.x >> 6);
    int b = widx >> 10, i = widx & 1023;
    int lane = threadIdx.x & 63;
    const float* hd = hid + b * 512;
    const ushort* w = mW2T + (long)i * 512;
    int j0 = lane * 8;
    short8v wv = *(const short8v*)&w[j0];
    float4 h0 = *(const float4*)&hd[j0];
    float4 h1 = *(const float4*)&hd[j0 + 4];
    float acc = bf2f((ushort)wv[0]) * h0.x + bf2f((ushort)wv[1]) * h0.y
              + bf2f((ushort)wv[2]) * h0.z + bf2f((ushort)wv[3]) * h0.w
              + bf2f((ushort)wv[4]) * h1.x + bf2f((ushort)wv[5]) * h1.y
              + bf2f((ushort)wv[6]) * h1.z + bf2f((ushort)wv[7]) * h1.w;
    #pragma unroll
    for (int off = 32; off; off >>= 1) acc += __shfl_xor(acc, off);
    if (lane == 0) {
        float v = base_metric[i] + 0.1f * (acc + mb2[i]);
        float sp = fmaxf(v, 0.f) + log1pf(expf(-fabsf(v)));
        metric[b * 1024 + i] = sp + 1e-6f;
    }
}

// ------- causal K-window + qn + hebbian + gate, LDS-tiled, fully fused -------
#define WLDR 67

__global__ __launch_bounds__(256) void window_kernel(
    const ushort* __restrict__ qs, const ushort* __restrict__ vs,
    const float* __restrict__ metric, const ushort* __restrict__ hebT,
    ushort* __restrict__ gated) {
    int tile = blockIdx.x, h = blockIdx.y, b = blockIdx.z;
    int t0 = tile * 32;
    int tid = threadIdx.x;
    __shared__ uint Qw[63 * WLDR];
    __shared__ uint Vw[63 * WLDR];
    __shared__ uint Qr[32 * 64];
    __shared__ float smf[HD_];
    if (tid < HD_) smf[tid] = sqrtf(metric[(b * H_ + h) * HD_ + tid]);
    __syncthreads();
    for (int i = tid; i < 63 * 64; i += 256) {
        int r = i >> 6, c = i & 63;
        int grow = t0 - 31 + r;
        uint qv = 0, vv = 0;
        if (grow >= 0) {
            long base = ((long)(b * T_ + grow) * N_ + h * HD_) >> 1;
            qv = ((const uint*)qs)[base + c];
            vv = ((const uint*)vs)[base + c];
        }
        float q0 = bf2f((ushort)(qv & 0xffff)) * smf[2 * c];
        float q1 = bf2f((ushort)(qv >> 16)) * smf[2 * c + 1];
        Qw[r * WLDR + c] = (uint)f2bf(q0) | ((uint)f2bf(q1) << 16);
        Vw[r * WLDR + c] = vv;
        if (r >= 31) Qr[(r - 31) * 64 + c] = qv;
    }
    __syncthreads();
    int w = tid >> 6, lane = tid & 63;
    int k = lane & 31, half = lane >> 5;
    // per-wave row norms (rows w*8 .. w*8+7)
    float invn[8];
    #pragma unroll
    for (int ri = 0; ri < 8; ++ri) {
        uint u = Qr[(w * 8 + ri) * 64 + lane];
        float a0 = bf2f((ushort)(u & 0xffff)), a1 = bf2f((ushort)(u >> 16));
        float nv = a0 * a0 + a1 * a1;
        #pragma unroll
        for (int off = 32; off; off >>= 1) nv += __shfl_xor(nv, off);
        invn[ri] = 1.0f / fmaxf(sqrtf(nv), 1e-12f);
    }
    // hebbian with raw q (normalize by invn scalar afterwards); heb[h] is L1-resident
    const ushort* hb = hebT + (long)h * HD_ * HD_;   // [e][dd]
    float hacc0[8] = {}, hacc1[8] = {};
    for (int dv = 0; dv < 16; ++dv) {
        short8v h0 = *(const short8v*)&hb[(2 * lane) * HD_ + dv * 8];
        short8v h1 = *(const short8v*)&hb[(2 * lane + 1) * HD_ + dv * 8];
        #pragma unroll
        for (int ri = 0; ri < 8; ++ri) {
            uint4 qu = *(const uint4*)&Qr[(w * 8 + ri) * 64 + dv * 4];
            float qd[8] = {bf2f((ushort)(qu.x & 0xffff)), bf2f((ushort)(qu.x >> 16)),
                           bf2f((ushort)(qu.y & 0xffff)), bf2f((ushort)(qu.y >> 16)),
                           bf2f((ushort)(qu.z & 0xffff)), bf2f((ushort)(qu.z >> 16)),
                           bf2f((ushort)(qu.w & 0xffff)), bf2f((ushort)(qu.w >> 16))};
            #pragma unroll
            for (int j = 0; j < 8; ++j) {
                hacc0[ri] = fmaf(qd[j], bf2f((ushort)h0[j]), hacc0[ri]);
                hacc1[ri] = fmaf(qd[j], bf2f((ushort)h1[j]), hacc1[ri]);
            }
        }
    }
    #pragma unroll 2
    for (int i = 0; i < 8; ++i) {
        int lt = w * 8 + i;
        int t = t0 + lt;
        const uint* qtrow = &Qw[(lt + 31) * WLDR + half * 32];
        const uint* qsrow = &Qw[(lt + k) * WLDR + half * 32];
        float val = 0.f;
        #pragma unroll
        for (int j = 0; j < 32; ++j) {
            uint a = qtrow[j], s = qsrow[j];
            float d0 = bf2f((ushort)(a & 0xffff)) - bf2f((ushort)(s & 0xffff));
            float d1 = bf2f((ushort)(a >> 16)) - bf2f((ushort)(s >> 16));
            val = fmaf(d0, d0, val);
            val = fmaf(d1, d1, val);
        }
        val += __shfl_xor(val, 32);
        float infl = __expf(-sqrtf(val + 1e-8f));
        float ws = infl;
        #pragma unroll
        for (int off = 16; off; off >>= 1) ws += __shfl_xor(ws, off);
        float wk = infl / (ws + 1e-8f);
        float c0 = hacc0[i] * invn[i], c1 = hacc1[i] * invn[i];
        #pragma unroll
        for (int kk = 0; kk < 32; ++kk) {
            float wkk = __shfl(wk, kk);
            uint vu = Vw[(lt + kk) * WLDR + lane];
            c0 = fmaf(wkk, bf2f((ushort)(vu & 0xffff)), c0);
            c1 = fmaf(wkk, bf2f((ushort)(vu >> 16)), c1);
        }
        uint qo = Qr[lt * 64 + lane];
        float g0 = bf2f((ushort)(qo & 0xffff)) * c0;
        float g1 = bf2f((ushort)(qo >> 16)) * c1;
        long rowb = (long)(b * T_ + t) * N_ + h * HD_;
        *(uint*)&gated[rowb + 2 * lane] = (uint)f2bf(g0) | ((uint)f2bf(g1) << 16);
    }
}

extern "C" void kernel_launch(void* const* d_in, const int* in_sizes, int n_in,
                              void* d_out, int out_size, void* d_ws, size_t ws_size,
                              hipStream_t stream) {
    const int*   tokens      = (const int*)  d_in[0];
    const float* emb         = (const float*)d_in[1];
    const float* field_init  = (const float*)d_in[2];
    const float* Wq          = (const float*)d_in[3];
    const float* Wv          = (const float*)d_in[4];
    const float* mW1         = (const float*)d_in[5];
    const float* mb1         = (const float*)d_in[6];
    const float* mW2         = (const float*)d_in[7];
    const float* mb2         = (const float*)d_in[8];
    const float* base_metric = (const float*)d_in[9];
    const float* decoder     = (const float*)d_in[10];
    const float* hebbian     = (const float*)d_in[11];
    const float* fW1         = (const float*)d_in[12];
    const float* fb1         = (const float*)d_in[13];
    const float* fW2         = (const float*)d_in[14];
    const float* fb2         = (const float*)d_in[15];
    const float* g1          = (const float*)d_in[16];
    const float* b1          = (const float*)d_in[17];
    const float* g2          = (const float*)d_in[18];
    const float* b2          = (const float*)d_in[19];
    const float* gf          = (const float*)d_in[20];
    const float* bf          = (const float*)d_in[21];
    const float* Wl          = (const float*)d_in[22];
    const float* bl          = (const float*)d_in[23];
    float* out = (float*)d_out;

    char* wp = (char*)d_ws;
    auto alloc = [&](size_t bytes) { char* p = wp; wp += (bytes + 255) & ~255UL; return p; };
    float*  x        = (float*) alloc(524288 * 4);
    ushort* y1_bf    = (ushort*)alloc(524288 * 2);
    ushort* y2_bf    = (ushort*)alloc(524288 * 2);
    ushort* yf_bf    = (ushort*)alloc(524288 * 2);
    ushort* qs_bf    = (ushort*)alloc(2097152 * 2);  // } WlT (16MB) aliases these
    ushort* vs_bf    = (ushort*)alloc(2097152 * 2);  // } four contiguous 4MB bufs
    ushort* gated_bf = (ushort*)alloc(2097152 * 2);  // }
    ushort* ffnh_bf  = (ushort*)alloc(2097152 * 2);  // }
    float*  dec_out  = (float*) alloc(524288 * 4);
    float*  ffn_out  = (float*) alloc(524288 * 4);
    ushort* WqT      = (ushort*)alloc(262144 * 2);
    ushort* WvT      = (ushort*)alloc(262144 * 2);
    ushort* decT     = (ushort*)alloc(262144 * 2);
    ushort* fW1T     = (ushort*)alloc(262144 * 2);
    ushort* fW2T     = (ushort*)alloc(262144 * 2);
    ushort* mW1T     = (ushort*)alloc(524288 * 2);
    ushort* mW2T     = (ushort*)alloc(524288 * 2);
    ushort* hebT     = (ushort*)alloc(131072 * 2);
    float*  ps       = (float*) alloc(16 * 1024 * 4);
    float*  ps8      = (float*) alloc(16 * 1024 * 4);
    float*  hid      = (float*) alloc(1024 * 4);
    float*  metricb  = (float*) alloc(2048 * 4);
    ushort* WlT      = (ushort*)qs_bf;               // 16MB over qs/vs/gated/ffnh

    TcastBatch tb;
    const float* tin[8]  = {Wq, Wv, decoder, fW1, fW2, mW1, mW2, hebbian};
    ushort*      tout[8] = {WqT, WvT, decT, fW1T, fW2T, mW1T, mW2T, hebT};
    long tinS[8]  = {256 * 128, 256 * 128, 0, 0, 0, 0, 0, 128 * 128};
    long toutS[8] = {128 * 256, 128 * 256, 0, 0, 0, 0, 0, 128 * 128};
    int tR[8] = {256, 256, 1024, 256, 1024, 1024, 512, 128};
    int tC[8] = {128, 128, 256, 1024, 256, 512, 1024, 128};
    int cum = 0;
    tb.cum[0] = 0;
    for (int i = 0; i < 8; ++i) {
        tb.in[i] = tin[i]; tb.out[i] = tout[i];
        tb.inS[i] = tinS[i]; tb.outS[i] = toutS[i];
        tb.R[i] = tR[i]; tb.C[i] = tC[i];
        tb.cb[i] = tC[i] / 64; tb.rb[i] = tR[i] / 64;
        int zc = (i == 0 || i == 1 || i == 7) ? 8 : 1;
        cum += tb.cb[i] * tb.rb[i] * zc;
        tb.cum[i + 1] = cum;
    }
    tcast_all_kernel<<<cum, 256, 0, stream>>>(tb);

    embed_rope_ln_kernel<<<B_ * T_, 256, 0, stream>>>(
        tokens, emb, field_init, g1, b1, g2, b2, x, y1_bf, y2_bf);

    for (int step = 0; step < 2; ++step) {
        if (step == 1)
            ln_kernel<<<B_ * T_, 256, 0, stream>>>(
                x, dec_out, ffn_out, g1, b1, g2, b2, y1_bf, y2_bf);
        gemm3_kernel<<<dim3(8, 16, 3), 256, 0, stream>>>(
            y1_bf, y2_bf, WqT, WvT, fW1T, fb1, qs_bf, vs_bf, ffnh_bf, ps, ps8);
        mlp1_kernel<<<256, 256, 0, stream>>>(ps, ps8, mW1T, mb1, hid);
        mlp2_kernel<<<512, 256, 0, stream>>>(hid, mW2T, mb2, base_metric, metricb);
        window_kernel<<<dim3(T_ / 32, H_, B_), 256, 0, stream>>>(
            qs_bf, vs_bf, metricb, hebT, gated_bf);
        gemm2_kernel<<<dim3(4, 32, 2), 256, 0, stream>>>(
            gated_bf, ffnh_bf, decT, fW2T, fb2, dec_out, ffn_out);
    }
    ln_kernel<<<B_ * T_, 256, 0, stream>>>(
        x, dec_out, ffn_out, gf, bf, nullptr, nullptr, yf_bf, nullptr);
    tcast_kernel<<<dim3(500, 4), 256, 0, stream>>>(Wl, WlT, 256, VOCAB_);
    vocab_kernel<<<4000, 256, 0, stream>>>(yf_bf, WlT, bl, out);
}

// Round 7
// 307.618 us; speedup vs baseline: 3.9728x; 1.0171x over previous
//
#include <hip/hip_runtime.h>
#include <hip/hip_bf16.h>
#include <math.h>

#define B_ 2
#define T_ 1024
#define D_ 256
#define N_ 1024
#define H_ 8
#define HD_ 128
#define K_ 32
#define VOCAB_ 32000

typedef __attribute__((ext_vector_type(8))) short short8v;
typedef __attribute__((ext_vector_type(4))) float f32x4;

static __device__ __forceinline__ float geluf(float x) {
    return 0.5f * x * (1.0f + erff(x * 0.70710678118654752f));
}

static __device__ __forceinline__ ushort f2bf(float f) {
    unsigned u = __builtin_bit_cast(unsigned, f);
    u += 0x7fff + ((u >> 16) & 1);
    return (ushort)(u >> 16);
}

static __device__ __forceinline__ float bf2f(ushort u) {
    unsigned v = ((unsigned)u) << 16;
    return __builtin_bit_cast(float, v);
}

// ---------------- fused embed + quantized RoPE + dual LayerNorm ----------------
__global__ void embed_rope_ln_kernel(const int* __restrict__ tokens,
                                     const float* __restrict__ emb,
                                     const float* __restrict__ field_init,
                                     const float* __restrict__ g1, const float* __restrict__ b1,
                                     const float* __restrict__ g2, const float* __restrict__ b2,
                                     float* __restrict__ x,
                                     ushort* __restrict__ y1, ushort* __restrict__ y2) {
    int bt = blockIdx.x;
    int d = threadIdx.x;
    int t = bt & (T_ - 1);
    int tok = tokens[bt];
    float v = emb[(long)tok * D_ + d] + field_init[d];
    float partner = __shfl_xor(v, 1);
    float rot = (d & 1) ? partner : -partner;
    float freq = exp2f(-0.0625f * (float)(d & ~1)) * (1.0f / 6.283185307179586f);
    float ph = fmodf((float)t * freq, 1.0f) * 6.283185307179586f;
    v = v * cosf(ph) + rot * sinf(ph);
    long i = (long)bt * D_ + d;
    x[i] = v;
    __shared__ float red[4];
    int lane = d & 63, wid = d >> 6;
    float s = v;
    #pragma unroll
    for (int off = 32; off; off >>= 1) s += __shfl_xor(s, off);
    if (lane == 0) red[wid] = s;
    __syncthreads();
    float mu = (red[0] + red[1] + red[2] + red[3]) * (1.0f / D_);
    float dv = v - mu;
    float s2 = dv * dv;
    #pragma unroll
    for (int off = 32; off; off >>= 1) s2 += __shfl_xor(s2, off);
    __syncthreads();
    if (lane == 0) red[wid] = s2;
    __syncthreads();
    float var = (red[0] + red[1] + red[2] + red[3]) * (1.0f / D_);
    float rstd = rsqrtf(var + 1e-5f);
    float nv = dv * rstd;
    y1[i] = f2bf(nv * g1[d] + b1[d]);
    y2[i] = f2bf(nv * g2[d] + b2[d]);
}

// ---------------- LayerNorm (+ residual add) -> bf16 outputs ----------------
__global__ void ln_kernel(float* __restrict__ x,
                          const float* __restrict__ addA, const float* __restrict__ addB,
                          const float* __restrict__ g1, const float* __restrict__ b1,
                          const float* __restrict__ g2, const float* __restrict__ b2,
                          ushort* __restrict__ y1, ushort* __restrict__ y2) {
    int row = blockIdx.x;
    int d = threadIdx.x;
    long i = (long)row * D_ + d;
    float v = x[i] + addA[i] + addB[i];
    x[i] = v;
    __shared__ float red[4];
    int lane = d & 63, wid = d >> 6;
    float s = v;
    #pragma unroll
    for (int off = 32; off; off >>= 1) s += __shfl_xor(s, off);
    if (lane == 0) red[wid] = s;
    __syncthreads();
    float mu = (red[0] + red[1] + red[2] + red[3]) * (1.0f / D_);
    float dv = v - mu;
    float s2 = dv * dv;
    #pragma unroll
    for (int off = 32; off; off >>= 1) s2 += __shfl_xor(s2, off);
    __syncthreads();
    if (lane == 0) red[wid] = s2;
    __syncthreads();
    float var = (red[0] + red[1] + red[2] + red[3]) * (1.0f / D_);
    float rstd = rsqrtf(var + 1e-5f);
    float nv = dv * rstd;
    y1[i] = f2bf(nv * g1[d] + b1[d]);
    if (y2) y2[i] = f2bf(nv * g2[d] + b2[d]);
}

// ---------------- transpose-cast tile body ----------------
static __device__ __forceinline__ void tcast_tile(
    const float* __restrict__ in, ushort* __restrict__ out,
    int R, int C, int ry, int cx) {
    __shared__ float sm[64][65];
    int r0 = ry * 64, c0 = cx * 64;
    int tx = threadIdx.x & 63, ty = threadIdx.x >> 6;
    #pragma unroll
    for (int i = 0; i < 16; ++i) {
        int r = i * 4 + ty;
        sm[r][tx] = in[(long)(r0 + r) * C + c0 + tx];
    }
    __syncthreads();
    #pragma unroll
    for (int i = 0; i < 16; ++i) {
        int c = i * 4 + ty;
        out[(long)(c0 + c) * R + r0 + tx] = f2bf(sm[tx][c]);
    }
}

__global__ __launch_bounds__(256) void tcast_kernel(
    const float* __restrict__ in, ushort* __restrict__ out, int R, int C) {
    tcast_tile(in, out, R, C, blockIdx.y, blockIdx.x);
}

struct TcastBatch {
    const float* in[8];
    ushort* out[8];
    long inS[8], outS[8];
    int cb[8], rb[8], R[8], C[8];
    int cum[9];
};

__global__ __launch_bounds__(256) void tcast_all_kernel(TcastBatch tb) {
    int bid = blockIdx.x;
    int d = 0;
    #pragma unroll
    for (int i = 0; i < 8; ++i) if (bid >= tb.cum[i + 1]) d = i + 1;
    int local = bid - tb.cum[d];
    int bpz = tb.cb[d] * tb.rb[d];
    int z = local / bpz;
    int rem = local - z * bpz;
    int cx = rem % tb.cb[d], ry = rem / tb.cb[d];
    tcast_tile(tb.in[d] + z * tb.inS[d], tb.out[d] + z * tb.outS[d],
               tb.R[d], tb.C[d], ry, cx);
}

// ================= 128x128 MFMA core, BK=64; LDS-staged epilogue; optional sig =====
#define LDK 72
#define CSTR 132

template<int ACT, int OUTBF, int SIG>
__device__ __forceinline__ void gemm128_core(
    const ushort* __restrict__ A, int lda,
    const ushort* __restrict__ Bt, int ldb,
    const float* __restrict__ bias, void* __restrict__ Cout, int ldc,
    int Kd, int bx, int by,
    float* __restrict__ psOut, float* __restrict__ ps8Out) {
    __shared__ __align__(16) ushort As[128 * LDK];
    __shared__ __align__(16) ushort Bs[128 * LDK];
    int tid = threadIdx.x;
    int wid = tid >> 6, lane = tid & 63;
    int brow = by * 128, bcol = bx * 128;
    int wr = wid >> 1, wc = wid & 1;
    f32x4 acc[4][4] = {};
    for (int k0 = 0; k0 < Kd; k0 += 64) {
        __syncthreads();
        #pragma unroll
        for (int j = 0; j < 4; ++j) {
            int idx = tid + j * 256;
            int r = idx >> 3, sgm = idx & 7;
            *(short8v*)&As[r * LDK + sgm * 8] =
                *(const short8v*)&A[(long)(brow + r) * lda + k0 + sgm * 8];
            *(short8v*)&Bs[r * LDK + sgm * 8] =
                *(const short8v*)&Bt[(long)(bcol + r) * ldb + k0 + sgm * 8];
        }
        __syncthreads();
        #pragma unroll
        for (int kk = 0; kk < 2; ++kk) {
            short8v af[4], bfv[4];
            #pragma unroll
            for (int m = 0; m < 4; ++m)
                af[m] = *(const short8v*)&As[(wr * 64 + m * 16 + (lane & 15)) * LDK + kk * 32 + (lane >> 4) * 8];
            #pragma unroll
            for (int n = 0; n < 4; ++n)
                bfv[n] = *(const short8v*)&Bs[(wc * 64 + n * 16 + (lane & 15)) * LDK + kk * 32 + (lane >> 4) * 8];
            #pragma unroll
            for (int m = 0; m < 4; ++m)
                #pragma unroll
                for (int n = 0; n < 4; ++n)
                    acc[m][n] = __builtin_amdgcn_mfma_f32_16x16x32_bf16(af[m], bfv[n], acc[m][n], 0, 0, 0);
        }
    }
    float* Cs = (float*)As;
    float cs = 0.f, cs8 = 0.f;
    #pragma unroll
    for (int chunk = 0; chunk < 4; ++chunk) {
        __syncthreads();
        if (wr == (chunk >> 1)) {
            #pragma unroll
            for (int mm = 0; mm < 2; ++mm) {
                int m = (chunk & 1) * 2 + mm;
                int lr0 = mm * 16 + ((lane >> 4) << 2);
                #pragma unroll
                for (int n = 0; n < 4; ++n) {
                    int lcol = wc * 64 + n * 16 + (lane & 15);
                    #pragma unroll
                    for (int j = 0; j < 4; ++j)
                        Cs[(lr0 + j) * CSTR + lcol] = acc[m][n][j];
                }
            }
        }
        __syncthreads();
        int lrow = tid >> 3, f4 = tid & 7;
        long grow = brow + chunk * 32 + lrow;
        if (OUTBF) {
            #pragma unroll
            for (int u = 0; u < 2; ++u) {
                int c0i = (f4 + u * 8) * 8;
                uint pk[4];
                #pragma unroll
                for (int q = 0; q < 4; ++q) {
                    int cc = c0i + 2 * q;
                    float v0 = Cs[lrow * CSTR + cc]     + (bias ? bias[bcol + cc] : 0.0f);
                    float v1 = Cs[lrow * CSTR + cc + 1] + (bias ? bias[bcol + cc + 1] : 0.0f);
                    if (ACT == 1) { v0 = fmaxf(v0, 0.0f); v1 = fmaxf(v1, 0.0f); }
                    else if (ACT == 2) { v0 = geluf(v0); v1 = geluf(v1); }
                    pk[q] = (uint)f2bf(v0) | ((uint)f2bf(v1) << 16);
                }
                *(uint4*)&((ushort*)Cout)[grow * ldc + bcol + c0i] = *(uint4*)pk;
            }
        } else {
            #pragma unroll
            for (int u = 0; u < 4; ++u) {
                int c0i = (f4 + u * 8) * 4;
                float vv[4];
                #pragma unroll
                for (int q = 0; q < 4; ++q) {
                    float v = Cs[lrow * CSTR + c0i + q] + (bias ? bias[bcol + c0i + q] : 0.0f);
                    if (ACT == 1) v = fmaxf(v, 0.0f);
                    else if (ACT == 2) v = geluf(v);
                    vv[q] = v;
                }
                *(float4*)&((float*)Cout)[grow * ldc + bcol + c0i] = *(float4*)vv;
            }
        }
        if (SIG && tid < 128) {
            #pragma unroll
            for (int r = 0; r < 32; ++r) {
                float vr = fmaxf(Cs[r * CSTR + tid], 0.0f);
                cs += vr;
                if ((r & 7) == 0) cs8 += vr;
            }
        }
    }
    if (SIG && tid < 128) {
        psOut[by * 1024 + bcol + tid] = cs;
        ps8Out[by * 1024 + bcol + tid] = cs8;
    }
}

// batched qs/vs/ffn1 (bf16 out); z=0 also emits sig partial sums
__global__ __launch_bounds__(256) void gemm3_kernel(
    const ushort* __restrict__ y1, const ushort* __restrict__ y2,
    const ushort* __restrict__ WqT, const ushort* __restrict__ WvT, const ushort* __restrict__ fW1T,
    const float* __restrict__ fb1,
    ushort* __restrict__ qs, ushort* __restrict__ vs, ushort* __restrict__ ffnh,
    float* __restrict__ ps, float* __restrict__ ps8) {
    int z = blockIdx.z;
    if (z == 0)
        gemm128_core<1, 1, 1>(y1, 256, WqT, 256, nullptr, qs, 1024, 256,
                              blockIdx.x, blockIdx.y, ps, ps8);
    else if (z == 1)
        gemm128_core<1, 1, 0>(y1, 256, WvT, 256, nullptr, vs, 1024, 256,
                              blockIdx.x, blockIdx.y, nullptr, nullptr);
    else
        gemm128_core<2, 1, 0>(y2, 256, fW1T, 256, fb1, ffnh, 1024, 256,
                              blockIdx.x, blockIdx.y, nullptr, nullptr);
}

// vocab projection with XCD-chunked block swizzle (grid 4000 = 8*500)
__global__ __launch_bounds__(256) void vocab_kernel(
    const ushort* __restrict__ yf, const ushort* __restrict__ WlT,
    const float* __restrict__ bl, float* __restrict__ out) {
    int g = blockIdx.x;
    int nid = (g & 7) * 500 + (g >> 3);
    gemm128_core<0, 0, 0>(yf, 256, WlT, 256, bl, out, VOCAB_, 256,
                          nid >> 4, nid & 15, nullptr, nullptr);
}

// ================= 64x64 MFMA core for N=256 GEMMs (decoder + FFN2) =============
__global__ __launch_bounds__(256) void gemm2_kernel(
    const ushort* __restrict__ gated, const ushort* __restrict__ ffnh,
    const ushort* __restrict__ decT, const ushort* __restrict__ fW2T,
    const float* __restrict__ fb2,
    float* __restrict__ dec_out, float* __restrict__ ffn_out) {
    int z = blockIdx.z;
    const ushort* A = z ? ffnh : gated;
    const ushort* Bt = z ? fW2T : decT;
    const float* bias = z ? fb2 : nullptr;
    float* C = z ? ffn_out : dec_out;
    const int Kd = 1024, N = 256;
    __shared__ __align__(16) ushort As[64 * LDK];
    __shared__ __align__(16) ushort Bs[64 * LDK];
    int tid = threadIdx.x;
    int wid = tid >> 6, lane = tid & 63;
    int brow = blockIdx.y * 64, bcol = blockIdx.x * 64;
    int wr = wid >> 1, wc = wid & 1;
    f32x4 acc[2][2] = {};
    for (int k0 = 0; k0 < Kd; k0 += 64) {
        __syncthreads();
        #pragma unroll
        for (int j = 0; j < 2; ++j) {
            int idx = tid + j * 256;
            int r = idx >> 3, sgm = idx & 7;
            *(short8v*)&As[r * LDK + sgm * 8] =
                *(const short8v*)&A[(long)(brow + r) * Kd + k0 + sgm * 8];
            *(short8v*)&Bs[r * LDK + sgm * 8] =
                *(const short8v*)&Bt[(long)(bcol + r) * Kd + k0 + sgm * 8];
        }
        __syncthreads();
        #pragma unroll
        for (int kk = 0; kk < 2; ++kk) {
            short8v af[2], bfv[2];
            #pragma unroll
            for (int m = 0; m < 2; ++m)
                af[m] = *(const short8v*)&As[(wr * 32 + m * 16 + (lane & 15)) * LDK + kk * 32 + (lane >> 4) * 8];
            #pragma unroll
            for (int n = 0; n < 2; ++n)
                bfv[n] = *(const short8v*)&Bs[(wc * 32 + n * 16 + (lane & 15)) * LDK + kk * 32 + (lane >> 4) * 8];
            #pragma unroll
            for (int m = 0; m < 2; ++m)
                #pragma unroll
                for (int n = 0; n < 2; ++n)
                    acc[m][n] = __builtin_amdgcn_mfma_f32_16x16x32_bf16(af[m], bfv[n], acc[m][n], 0, 0, 0);
        }
    }
    int r0 = brow + wr * 32 + ((lane >> 4) << 2);
    int c0 = bcol + wc * 32 + (lane & 15);
    #pragma unroll
    for (int n = 0; n < 2; ++n) {
        int col = c0 + n * 16;
        float bv = bias ? bias[col] : 0.0f;
        #pragma unroll
        for (int m = 0; m < 2; ++m)
            #pragma unroll
            for (int j = 0; j < 4; ++j)
                C[(long)(r0 + m * 16 + j) * N + col] = acc[m][n][j] + bv;
    }
}

// ---------------- metric MLP stage 1 (fused ps reduction) ----------------
__global__ __launch_bounds__(256) void mlp1_kernel(
    const float* __restrict__ ps, const float* __restrict__ ps8,
    const ushort* __restrict__ mW1T, const float* __restrict__ mb1,
    float* __restrict__ hid) {
    int blk = blockIdx.x;
    int b = blk >> 7;
    __shared__ float sig_l[1024];
    int tid = threadIdx.x;
    for (int c = tid; c < 1024; c += 256) {
        float s = 0.f, s8 = 0.f;
        #pragma unroll
        for (int by8 = 0; by8 < 8; ++by8) {
            s += ps[(b * 8 + by8) * 1024 + c];
            s8 += ps8[(b * 8 + by8) * 1024 + c];
        }
        sig_l[c] = s * (1.0f / 1024.0f) + 0.5f * s8 * (1.0f / 128.0f);
    }
    __syncthreads();
    int wv = tid >> 6, lane = tid & 63;
    int j = (blk & 127) * 4 + wv;
    const ushort* wrow = mW1T + (long)j * 1024;
    float acc = 0.f;
    #pragma unroll
    for (int c2 = 0; c2 < 4; ++c2) {
        int n0 = c2 * 256 + lane * 4;
        float4 sv = *(const float4*)&sig_l[n0];
        ushort4 w4 = *(const ushort4*)&wrow[n0];
        acc += bf2f(w4.x) * sv.x + bf2f(w4.y) * sv.y
             + bf2f(w4.z) * sv.z + bf2f(w4.w) * sv.w;
    }
    #pragma unroll
    for (int off = 32; off; off >>= 1) acc += __shfl_xor(acc, off);
    if (lane == 0) hid[b * 512 + j] = geluf(acc + mb1[j]);
}

__global__ __launch_bounds__(256) void mlp2_kernel(
    const float* __restrict__ hid, const ushort* __restrict__ mW2T,
    const float* __restrict__ mb2, const float* __restrict__ base_metric,
    float* __restrict__ metric) {
    int widx = blockIdx.x * 4 + (threadIdx.x >> 6);
    int b = widx >> 10, i = widx & 1023;
    int lane = threadIdx.x & 63;
    const float* hd = hid + b * 512;
    const ushort* w = mW2T + (long)i * 512;
    int j0 = lane * 8;
    short8v wv = *(const short8v*)&w[j0];
    float4 h0 = *(const float4*)&hd[j0];
    float4 h1 = *(const float4*)&hd[j0 + 4];
    float acc = bf2f((ushort)wv[0]) * h0.x + bf2f((ushort)wv[1]) * h0.y
              + bf2f((ushort)wv[2]) * h0.z + bf2f((ushort)wv[3]) * h0.w
              + bf2f((ushort)wv[4]) * h1.x + bf2f((ushort)wv[5]) * h1.y
              + bf2f((ushort)wv[6]) * h1.z + bf2f((ushort)wv[7]) * h1.w;
    #pragma unroll
    for (int off = 32; off; off >>= 1) acc += __shfl_xor(acc, off);
    if (lane == 0) {
        float v = base_metric[i] + 0.1f * (acc + mb2[i]);
        float sp = fmaxf(v, 0.f) + log1pf(expf(-fabsf(v)));
        metric[b * 1024 + i] = sp + 1e-6f;
    }
}

// ======== causal K-window via MFMA (norm-trick QK^T, banded softmax, MFMA PV+heb) ====
// per block: 16 t-rows, one (h,b). LDS ~46KB.
#define QLD 136      // ushort stride for Qt/Qr rows (17*8 -> 16B aligned, 2-way banks)
#define QLDU 68
#define VLD 72       // Vt [e][s] stride
#define PLD 72       // P [t][s] stride
#define CLD 132      // ctx f32 stride

__global__ __launch_bounds__(256) void window_kernel(
    const ushort* __restrict__ qs, const ushort* __restrict__ vs,
    const float* __restrict__ metric, const ushort* __restrict__ hebT,
    ushort* __restrict__ gated) {
    int tile = blockIdx.x, h = blockIdx.y, b = blockIdx.z;
    int t0 = tile * 16;
    int tid = threadIdx.x;
    __shared__ __align__(16) ushort Qt[48 * QLD];   // sqrt(m)-scaled q, rows t0-31..t0+15 (row47 zero)
    __shared__ __align__(16) ushort Qr[16 * QLD];   // raw q rows t0..t0+15
    __shared__ __align__(16) ushort Vt[128 * VLD];  // V^T [e][s], s 0..63
    __shared__ __align__(16) ushort P[16 * PLD];    // P [t][s]
    __shared__ float ctx[16 * CLD];
    __shared__ float ns[48], invn_l[16], part[3][16], smf[128];

    if (tid < 128) smf[tid] = sqrtf(metric[(b * H_ + h) * HD_ + tid]);
    if (tid < 128) { int t = tid >> 3, c = tid & 7; ((uint*)P)[t * 36 + 24 + c] = 0; }
    __syncthreads();

    // stage Qt (scaled bf16) + Qr (raw)
    for (int i = tid; i < 48 * 64; i += 256) {
        int r = i >> 6, c = i & 63;
        int grow = t0 - 31 + r;
        uint qv = 0;
        if (r < 47 && grow >= 0)
            qv = ((const uint*)qs)[(((long)(b * T_ + grow) * N_ + h * HD_) >> 1) + c];
        float q0 = bf2f((ushort)(qv & 0xffff)) * smf[2 * c];
        float q1 = bf2f((ushort)(qv >> 16)) * smf[2 * c + 1];
        ((uint*)Qt)[r * QLDU + c] = (uint)f2bf(q0) | ((uint)f2bf(q1) << 16);
        if (r >= 31 && r < 47) ((uint*)Qr)[(r - 31) * QLDU + c] = qv;
    }
    // stage Vt transposed (paired rows); zero rows s>=47 / grow<0
    for (int i = tid; i < 32 * 64; i += 256) {
        int r2 = i >> 6, c = i & 63;
        int ra = 2 * r2, rb_ = 2 * r2 + 1;
        int ga = t0 - 31 + ra, gb = t0 - 31 + rb_;
        uint v0 = 0, v1 = 0;
        if (ra < 47 && ga >= 0)
            v0 = ((const uint*)vs)[(((long)(b * T_ + ga) * N_ + h * HD_) >> 1) + c];
        if (rb_ < 47 && gb >= 0)
            v1 = ((const uint*)vs)[(((long)(b * T_ + gb) * N_ + h * HD_) >> 1) + c];
        ((uint*)Vt)[(2 * c) * 36 + r2]     = (v0 & 0xffff) | ((v1 & 0xffff) << 16);
        ((uint*)Vt)[(2 * c + 1) * 36 + r2] = (v0 >> 16) | (v1 & 0xffff0000u);
    }
    __syncthreads();

    int w = tid >> 6, lane = tid & 63;
    int lc = lane & 15, lr = lane >> 4;

    // row norms: 48 scaled (ns) + 16 raw (invn)
    for (int rr = 0; rr < 16; ++rr) {
        int row = w * 16 + rr;
        uint u = (row < 48) ? ((uint*)Qt)[row * QLDU + lane]
                            : ((uint*)Qr)[(row - 48) * QLDU + lane];
        float a0 = bf2f((ushort)(u & 0xffff)), a1 = bf2f((ushort)(u >> 16));
        float nv = a0 * a0 + a1 * a1;
        #pragma unroll
        for (int off = 32; off; off >>= 1) nv += __shfl_xor(nv, off);
        if (lane == 0) {
            if (row < 48) ns[row] = nv;
            else invn_l[row - 48] = 1.0f / fmaxf(sqrtf(nv), 1e-12f);
        }
    }
    __syncthreads();

    // QK^T: waves 0-2, m-tile w (16 s-rows each), n-tile = 16 t-cols
    f32x4 accS = {};
    if (w < 3) {
        #pragma unroll
        for (int k = 0; k < 4; ++k) {
            short8v a = *(const short8v*)&Qt[(w * 16 + lc) * QLD + k * 32 + lr * 8];
            short8v bf_ = *(const short8v*)&Qt[(31 + lc) * QLD + k * 32 + lr * 8];
            accS = __builtin_amdgcn_mfma_f32_16x16x32_bf16(a, bf_, accS, 0, 0, 0);
        }
    }
    // hebbian: all waves, n-tiles w*2, w*2+1 (B-fragments straight from global hebT)
    f32x4 accH[2] = {};
    const ushort* hb = hebT + (long)h * HD_ * HD_;
    #pragma unroll
    for (int nt = 0; nt < 2; ++nt)
        #pragma unroll
        for (int k = 0; k < 4; ++k) {
            short8v a = *(const short8v*)&Qr[lc * QLD + k * 32 + lr * 8];
            short8v bf_ = *(const short8v*)&hb[(long)((w * 2 + nt) * 16 + lc) * HD_ + k * 32 + lr * 8];
            accH[nt] = __builtin_amdgcn_mfma_f32_16x16x32_bf16(a, bf_, accH[nt], 0, 0, 0);
        }
    #pragma unroll
    for (int nt = 0; nt < 2; ++nt)
        #pragma unroll
        for (int j = 0; j < 4; ++j) {
            int t = lr * 4 + j;
            ctx[t * CLD + (w * 2 + nt) * 16 + lc] = accH[nt][j] * invn_l[t];
        }
    // banded softmax partials
    float wgt[4];
    if (w < 3) {
        float nt_ = ns[31 + lc];
        float psum = 0.f;
        #pragma unroll
        for (int j = 0; j < 4; ++j) {
            int s = w * 16 + lr * 4 + j;
            float val = fmaxf(nt_ + ns[s] - 2.0f * accS[j], 0.0f) + 1e-8f;
            bool band = (s >= lc) && (s <= lc + 31);
            wgt[j] = band ? __expf(-sqrtf(val)) : 0.0f;
            psum += wgt[j];
        }
        psum += __shfl_xor(psum, 16);
        psum += __shfl_xor(psum, 32);
        if (lane < 16) part[w][lane] = psum;
    }
    __syncthreads();
    if (w < 3) {
        float inv = 1.0f / (part[0][lc] + part[1][lc] + part[2][lc] + 1e-8f);
        uint lo = (uint)f2bf(wgt[0] * inv) | ((uint)f2bf(wgt[1] * inv) << 16);
        uint hi = (uint)f2bf(wgt[2] * inv) | ((uint)f2bf(wgt[3] * inv) << 16);
        uint2 pk = {lo, hi};
        *(uint2*)&P[lc * PLD + w * 16 + lr * 4] = pk;
    }
    __syncthreads();
    // PV: all waves, m-tiles w*2, w*2+1 (e rows); K=64 over s
    f32x4 accP[2] = {};
    #pragma unroll
    for (int mt = 0; mt < 2; ++mt)
        #pragma unroll
        for (int k = 0; k < 2; ++k) {
            short8v a = *(const short8v*)&Vt[((w * 2 + mt) * 16 + lc) * VLD + k * 32 + lr * 8];
            short8v bf_ = *(const short8v*)&P[lc * PLD + k * 32 + lr * 8];
            accP[mt] = __builtin_amdgcn_mfma_f32_16x16x32_bf16(a, bf_, accP[mt], 0, 0, 0);
        }
    #pragma unroll
    for (int mt = 0; mt < 2; ++mt)
        #pragma unroll
        for (int j = 0; j < 4; ++j) {
            int e = (w * 2 + mt) * 16 + lr * 4 + j;
            ctx[lc * CLD + e] += accP[mt][j];
        }
    __syncthreads();
    // gate with raw q, coalesced write
    {
        int t = tid >> 4, g = tid & 15;
        uint4 qu = *(const uint4*)&((const uint*)Qr)[t * QLDU + g * 4];
        const float* crow = &ctx[t * CLD + g * 8];
        uint qa[4] = {qu.x, qu.y, qu.z, qu.w};
        uint outp[4];
        #pragma unroll
        for (int q4 = 0; q4 < 4; ++q4) {
            float e0 = bf2f((ushort)(qa[q4] & 0xffff)) * crow[2 * q4];
            float e1 = bf2f((ushort)(qa[q4] >> 16))   * crow[2 * q4 + 1];
            outp[q4] = (uint)f2bf(e0) | ((uint)f2bf(e1) << 16);
        }
        *(uint4*)&gated[(long)(b * T_ + t0 + t) * N_ + h * HD_ + g * 8] = *(uint4*)outp;
    }
}

extern "C" void kernel_launch(void* const* d_in, const int* in_sizes, int n_in,
                              void* d_out, int out_size, void* d_ws, size_t ws_size,
                              hipStream_t stream) {
    const int*   tokens      = (const int*)  d_in[0];
    const float* emb         = (const float*)d_in[1];
    const float* field_init  = (const float*)d_in[2];
    const float* Wq          = (const float*)d_in[3];
    const float* Wv          = (const float*)d_in[4];
    const float* mW1         = (const float*)d_in[5];
    const float* mb1         = (const float*)d_in[6];
    const float* mW2         = (const float*)d_in[7];
    const float* mb2         = (const float*)d_in[8];
    const float* base_metric = (const float*)d_in[9];
    const float* decoder     = (const float*)d_in[10];
    const float* hebbian     = (const float*)d_in[11];
    const float* fW1         = (const float*)d_in[12];
    const float* fb1         = (const float*)d_in[13];
    const float* fW2         = (const float*)d_in[14];
    const float* fb2         = (const float*)d_in[15];
    const float* g1          = (const float*)d_in[16];
    const float* b1          = (const float*)d_in[17];
    const float* g2          = (const float*)d_in[18];
    const float* b2          = (const float*)d_in[19];
    const float* gf          = (const float*)d_in[20];
    const float* bf          = (const float*)d_in[21];
    const float* Wl          = (const float*)d_in[22];
    const float* bl          = (const float*)d_in[23];
    float* out = (float*)d_out;

    char* wp = (char*)d_ws;
    auto alloc = [&](size_t bytes) { char* p = wp; wp += (bytes + 255) & ~255UL; return p; };
    float*  x        = (float*) alloc(524288 * 4);
    ushort* y1_bf    = (ushort*)alloc(524288 * 2);
    ushort* y2_bf    = (ushort*)alloc(524288 * 2);
    ushort* yf_bf    = (ushort*)alloc(524288 * 2);
    ushort* qs_bf    = (ushort*)alloc(2097152 * 2);  // } WlT (16MB) aliases these
    ushort* vs_bf    = (ushort*)alloc(2097152 * 2);  // } four contiguous 4MB bufs
    ushort* gated_bf = (ushort*)alloc(2097152 * 2);  // }
    ushort* ffnh_bf  = (ushort*)alloc(2097152 * 2);  // }
    float*  dec_out  = (float*) alloc(524288 * 4);
    float*  ffn_out  = (float*) alloc(524288 * 4);
    ushort* WqT      = (ushort*)alloc(262144 * 2);
    ushort* WvT      = (ushort*)alloc(262144 * 2);
    ushort* decT     = (ushort*)alloc(262144 * 2);
    ushort* fW1T     = (ushort*)alloc(262144 * 2);
    ushort* fW2T     = (ushort*)alloc(262144 * 2);
    ushort* mW1T     = (ushort*)alloc(524288 * 2);
    ushort* mW2T     = (ushort*)alloc(524288 * 2);
    ushort* hebT     = (ushort*)alloc(131072 * 2);
    float*  ps       = (float*) alloc(16 * 1024 * 4);
    float*  ps8      = (float*) alloc(16 * 1024 * 4);
    float*  hid      = (float*) alloc(1024 * 4);
    float*  metricb  = (float*) alloc(2048 * 4);
    ushort* WlT      = (ushort*)qs_bf;               // 16MB over qs/vs/gated/ffnh

    TcastBatch tb;
    const float* tin[8]  = {Wq, Wv, decoder, fW1, fW2, mW1, mW2, hebbian};
    ushort*      tout[8] = {WqT, WvT, decT, fW1T, fW2T, mW1T, mW2T, hebT};
    long tinS[8]  = {256 * 128, 256 * 128, 0, 0, 0, 0, 0, 128 * 128};
    long toutS[8] = {128 * 256, 128 * 256, 0, 0, 0, 0, 0, 128 * 128};
    int tR[8] = {256, 256, 1024, 256, 1024, 1024, 512, 128};
    int tC[8] = {128, 128, 256, 1024, 256, 512, 1024, 128};
    int cum = 0;
    tb.cum[0] = 0;
    for (int i = 0; i < 8; ++i) {
        tb.in[i] = tin[i]; tb.out[i] = tout[i];
        tb.inS[i] = tinS[i]; tb.outS[i] = toutS[i];
        tb.R[i] = tR[i]; tb.C[i] = tC[i];
        tb.cb[i] = tC[i] / 64; tb.rb[i] = tR[i] / 64;
        int zc = (i == 0 || i == 1 || i == 7) ? 8 : 1;
        cum += tb.cb[i] * tb.rb[i] * zc;
        tb.cum[i + 1] = cum;
    }
    tcast_all_kernel<<<cum, 256, 0, stream>>>(tb);

    embed_rope_ln_kernel<<<B_ * T_, 256, 0, stream>>>(
        tokens, emb, field_init, g1, b1, g2, b2, x, y1_bf, y2_bf);

    for (int step = 0; step < 2; ++step) {
        if (step == 1)
            ln_kernel<<<B_ * T_, 256, 0, stream>>>(
                x, dec_out, ffn_out, g1, b1, g2, b2, y1_bf, y2_bf);
        gemm3_kernel<<<dim3(8, 16, 3), 256, 0, stream>>>(
            y1_bf, y2_bf, WqT, WvT, fW1T, fb1, qs_bf, vs_bf, ffnh_bf, ps, ps8);
        mlp1_kernel<<<256, 256, 0, stream>>>(ps, ps8, mW1T, mb1, hid);
        mlp2_kernel<<<512, 256, 0, stream>>>(hid, mW2T, mb2, base_metric, metricb);
        window_kernel<<<dim3(T_ / 16, H_, B_), 256, 0, stream>>>(
            qs_bf, vs_bf, metricb, hebT, gated_bf);
        gemm2_kernel<<<dim3(4, 32, 2), 256, 0, stream>>>(
            gated_bf, ffnh_bf, decT, fW2T, fb2, dec_out, ffn_out);
    }
    ln_kernel<<<B_ * T_, 256, 0, stream>>>(
        x, dec_out, ffn_out, gf, bf, nullptr, nullptr, yf_bf, nullptr);
    tcast_kernel<<<dim3(500, 4), 256, 0, stream>>>(Wl, WlT, 256, VOCAB_);
    vocab_kernel<<<4000, 256, 0, stream>>>(yf_bf, WlT, bl, out);
}